// Round 21
// baseline (1657.806 us; speedup 1.0000x reference)
//
#include <hip/hip_runtime.h>

#define EPSN 1e-6f

typedef __attribute__((ext_vector_type(4))) float f32x4;
typedef __attribute__((ext_vector_type(8))) __bf16 bf16x8;
typedef __attribute__((ext_vector_type(8))) unsigned short us8;
typedef __attribute__((ext_vector_type(4))) unsigned short us4;
typedef __attribute__((ext_vector_type(4))) float f4v;

__device__ __forceinline__ void async16(const void* g, void* l) {
  __builtin_amdgcn_global_load_lds(
      (const __attribute__((address_space(1))) unsigned int*)g,
      (__attribute__((address_space(3))) unsigned int*)l, 16, 0, 0);
}

// 2-level bf16 split: v ~= h + m with residual <= 2^-18 rel
__device__ __forceinline__ void split2(float v, unsigned short& h, unsigned short& m) {
  __bf16 a = (__bf16)v;  float fa = (float)a;
  __bf16 b = (__bf16)(v - fa);
  h = __builtin_bit_cast(unsigned short, a);
  m = __builtin_bit_cast(unsigned short, b);
}

// ---- x -> split pair (elementwise)
__global__ void k_splitx(const float* __restrict__ in, unsigned short* __restrict__ oh,
                         unsigned short* __restrict__ om, int n4) {
  int i = blockIdx.x * 256 + threadIdx.x;
  if (i < n4) {
    f4v v = ((const f4v*)in)[i];
    us4 h, m;
#pragma unroll
    for (int j = 0; j < 4; ++j) { unsigned short a, b; split2(v[j], a, b); h[j] = a; m[j] = b; }
    ((us4*)oh)[i] = h;
    ((us4*)om)[i] = m;
  }
}

// ==== kgm: 128^2-tile 3-term split GEMM (hh+hm+mh) — convs only (r18-proven) ====
__global__ __launch_bounds__(256, 2) void kgm(
    const unsigned short* __restrict__ Ah0, const unsigned short* __restrict__ Am0,
    const unsigned short* __restrict__ Ah1, const unsigned short* __restrict__ Am1,
    const float* __restrict__ B0, const float* __restrict__ B1,
    int lda, int N, int Mrows, int kchunk, float* __restrict__ outp) {
  __shared__ unsigned short lsA[2][2 * 128 * 32];
  __shared__ unsigned short lsB[2 * 4 * 128 * 8];
  const int tid = threadIdx.x, lane = tid & 63, wid = tid >> 6;
  const int n0 = blockIdx.x * 128, m0 = blockIdx.y * 128;
  const int kbase = blockIdx.z * kchunk;

  const unsigned short *Ah, *Am; const float* B; int koff;
  if (kbase < 2048) { Ah = Ah0; Am = Am0; B = B0; koff = kbase; }
  else              { Ah = Ah1; Am = Am1; B = B1; koff = kbase - 2048; }
  const int nt = kchunk >> 5;

  const unsigned short* asrc[4];
  int adst[4];
#pragma unroll
  for (int j = 0; j < 4; ++j) {
    int idx = j * 256 + tid;
    int s = idx >> 9, rem = idx & 511, row = rem >> 2, slot = idx & 3;
    const unsigned short* base = (s == 0) ? Ah : Am;
    asrc[j] = base + (size_t)(m0 + row) * lda + koff + ((slot ^ ((row >> 1) & 3)) << 3);
    adst[j] = (j * 256 + (tid & ~63)) * 16;
  }
  auto STAGEA = [&](int buf) {
#pragma unroll
    for (int j = 0; j < 4; ++j) {
      async16(asrc[j], (char*)&lsA[buf][0] + adst[j]);
      asrc[j] += 32;
    }
  };

  const int kq = tid >> 6, nn = tid & 63;
  const float* bptr = B + (size_t)(koff + kq * 8) * N + n0 + nn;
  const int bo0 = kq * 1024 + nn * 8;
  const int bo1 = kq * 1024 + (nn + 64) * 8;
  float bwa[8], bwb[8];
  us8 bs[4];
  auto LOADB = [&]() {
#pragma unroll
    for (int r = 0; r < 8; ++r) {
      bwa[r] = bptr[(size_t)r * N];
      bwb[r] = bptr[(size_t)r * N + 64];
    }
    bptr += (size_t)32 * N;
  };
  auto SPLITB = [&]() {
#pragma unroll
    for (int r = 0; r < 8; ++r) {
      unsigned short h, m;
      split2(bwa[r], h, m);
      bs[0][r] = h; bs[1][r] = m;
      split2(bwb[r], h, m);
      bs[2][r] = h; bs[3][r] = m;
    }
  };
  auto WRITEB = [&]() {
    *(us8*)&lsB[bo0] = bs[0];
    *(us8*)&lsB[4096 + bo0] = bs[1];
    *(us8*)&lsB[bo1] = bs[2];
    *(us8*)&lsB[4096 + bo1] = bs[3];
  };

  const int c0 = lane >> 4, l15 = lane & 15;
  const int wm = wid >> 1, wn = wid & 1;
  f32x4 acc[4][4];
#pragma unroll
  for (int i = 0; i < 4; ++i)
#pragma unroll
    for (int j = 0; j < 4; ++j) acc[i][j] = (f32x4){0, 0, 0, 0};

  STAGEA(0);
  LOADB();
  SPLITB();
  int abuf = 0;
  for (int t = 0; t < nt; ++t) {
    __syncthreads();
    WRITEB();
    __syncthreads();
    bool more = (t + 1 < nt);
    if (more) {
      STAGEA(abuf ^ 1);
      LOADB();
    }
    bf16x8 a[4][2];
#pragma unroll
    for (int mf = 0; mf < 4; ++mf) {
      int m = wm * 64 + mf * 16 + l15;
      int ro = m * 32 + ((c0 ^ ((m >> 1) & 3)) << 3);
      a[mf][0] = *(const bf16x8*)&lsA[abuf][ro];
      a[mf][1] = *(const bf16x8*)&lsA[abuf][4096 + ro];
    }
#pragma unroll
    for (int nf = 0; nf < 4; ++nf) {
      int ro = c0 * 1024 + (wn * 64 + nf * 16 + l15) * 8;
      bf16x8 b0 = *(const bf16x8*)&lsB[ro];
      bf16x8 b1 = *(const bf16x8*)&lsB[4096 + ro];
#pragma unroll
      for (int mf = 0; mf < 4; ++mf) {
        acc[mf][nf] = __builtin_amdgcn_mfma_f32_16x16x32_bf16(a[mf][0], b0, acc[mf][nf], 0, 0, 0);
        acc[mf][nf] = __builtin_amdgcn_mfma_f32_16x16x32_bf16(a[mf][1], b0, acc[mf][nf], 0, 0, 0);
        acc[mf][nf] = __builtin_amdgcn_mfma_f32_16x16x32_bf16(a[mf][0], b1, acc[mf][nf], 0, 0, 0);
      }
    }
    if (more) SPLITB();
    abuf ^= 1;
  }

#pragma unroll
  for (int mf = 0; mf < 4; ++mf)
#pragma unroll
    for (int nf = 0; nf < 4; ++nf)
#pragma unroll
      for (int r = 0; r < 4; ++r) {
        int m = m0 + wm * 64 + mf * 16 + c0 * 4 + r;
        int n = n0 + wn * 64 + nf * 16 + l15;
        outp[((size_t)blockIdx.z * Mrows + m) * N + n] = acc[mf][nf][r];
      }
}

// ==== kgm2: 256m x 128n tile, A DIRECT-FROM-GLOBAL (L2-resident), B LDS — cells ====
// 512 thr / 8 waves, wave tile 64x64, BK=32. A frag loads: per instr lanes form
// 16 rows x 64B = 16 full cache lines (coalesced). Only B in LDS (2x16KB dbuf);
// barrier drain needs lgkmcnt only.
__global__ __launch_bounds__(512, 1) void kgm2(
    const unsigned short* __restrict__ Ah0, const unsigned short* __restrict__ Am0,
    const unsigned short* __restrict__ Ah1, const unsigned short* __restrict__ Am1,
    const float* __restrict__ B0, const float* __restrict__ B1,
    int Mrows, int kchunk, float* __restrict__ outp) {
  __shared__ unsigned short lsB[2][2 * 4 * 128 * 8];  // [buf][split][kq][n128][8k]
  const int tid = threadIdx.x, lane = tid & 63, wid = tid >> 6;
  const int n0 = blockIdx.x * 128, m0 = blockIdx.y * 256;
  const int kbase = blockIdx.z * kchunk;

  const unsigned short *Ah, *Am; const float* B; int koff;
  if (kbase < 2048) { Ah = Ah0; Am = Am0; B = B0; koff = kbase; }
  else              { Ah = Ah1; Am = Am1; B = B1; koff = kbase - 2048; }
  const int nt = kchunk >> 5;

  const int c0 = lane >> 4, l15 = lane & 15;
  const int wm = wid >> 1, wn = wid & 1;

  // A: direct per-lane fragment pointers (row = wm*64+mf*16+l15, 16B slot = c0*8)
  const unsigned short* ap[4][2];
#pragma unroll
  for (int mf = 0; mf < 4; ++mf) {
    size_t off = (size_t)(m0 + wm * 64 + mf * 16 + l15) * 2048 + koff + c0 * 8;
    ap[mf][0] = Ah + off;
    ap[mf][1] = Am + off;
  }

  const int kq = tid >> 7, nn = tid & 127;
  const float* bptr = B + (size_t)(koff + kq * 8) * 8192 + n0 + nn;
  const int bo = kq * 1024 + nn * 8;
  float bw[8];
  us8 bsh, bsm;
  auto LOADB = [&]() {
#pragma unroll
    for (int r = 0; r < 8; ++r) bw[r] = bptr[(size_t)r * 8192];
    bptr += (size_t)32 * 8192;
  };
  auto SPLITB = [&]() {
#pragma unroll
    for (int r = 0; r < 8; ++r) {
      unsigned short h, m;
      split2(bw[r], h, m);
      bsh[r] = h; bsm[r] = m;
    }
  };
  auto WRITEB = [&](int buf) {
    *(us8*)&lsB[buf][bo] = bsh;
    *(us8*)&lsB[buf][4096 + bo] = bsm;
  };

  f32x4 acc[4][4];
#pragma unroll
  for (int i = 0; i < 4; ++i)
#pragma unroll
    for (int j = 0; j < 4; ++j) acc[i][j] = (f32x4){0, 0, 0, 0};

  LOADB();
  SPLITB();
  WRITEB(0);
  asm volatile("s_waitcnt lgkmcnt(0)" ::: "memory");
  __builtin_amdgcn_s_barrier();
  __builtin_amdgcn_sched_barrier(0);

  int cur = 0;
  for (int t = 0; t < nt; ++t) {
    bool more = (t + 1 < nt);
    if (more) LOADB();  // B(t+1) -> regs
    // A fragments for this k-chunk: direct global (L2/L1-hit)
    bf16x8 a[4][2];
#pragma unroll
    for (int mf = 0; mf < 4; ++mf) {
      a[mf][0] = *(const bf16x8*)ap[mf][0];
      a[mf][1] = *(const bf16x8*)ap[mf][1];
      ap[mf][0] += 32; ap[mf][1] += 32;
    }
#pragma unroll
    for (int nf = 0; nf < 4; ++nf) {
      int ro = c0 * 1024 + (wn * 64 + nf * 16 + l15) * 8;
      bf16x8 b0 = *(const bf16x8*)&lsB[cur][ro];
      bf16x8 b1 = *(const bf16x8*)&lsB[cur][4096 + ro];
#pragma unroll
      for (int mf = 0; mf < 4; ++mf) {
        acc[mf][nf] = __builtin_amdgcn_mfma_f32_16x16x32_bf16(a[mf][0], b0, acc[mf][nf], 0, 0, 0);
        acc[mf][nf] = __builtin_amdgcn_mfma_f32_16x16x32_bf16(a[mf][1], b0, acc[mf][nf], 0, 0, 0);
        acc[mf][nf] = __builtin_amdgcn_mfma_f32_16x16x32_bf16(a[mf][0], b1, acc[mf][nf], 0, 0, 0);
      }
    }
    if (more) {
      SPLITB();
      WRITEB(cur ^ 1);  // other buffer: no conflict with readers of cur
    }
    asm volatile("s_waitcnt lgkmcnt(0)" ::: "memory");
    __builtin_amdgcn_s_barrier();
    __builtin_amdgcn_sched_barrier(0);
    cur ^= 1;
  }

  // C/D: col = lane&15, row = (lane>>4)*4 + r  [m89-verified]
#pragma unroll
  for (int mf = 0; mf < 4; ++mf)
#pragma unroll
    for (int nf = 0; nf < 4; ++nf)
#pragma unroll
      for (int r = 0; r < 4; ++r) {
        int m = m0 + wm * 64 + mf * 16 + c0 * 4 + r;
        int n = n0 + wn * 64 + nf * 16 + l15;
        outp[((size_t)blockIdx.z * Mrows + m) * 8192 + n] = acc[mf][nf][r];
      }
}

// ==== kgm2b: 256x256 tile, A direct-from-global, wave tile 64x128 — ZX ====
__global__ __launch_bounds__(512, 1) void kgm2b(
    const unsigned short* __restrict__ Ah0, const unsigned short* __restrict__ Am0,
    const unsigned short* __restrict__ Ah1, const unsigned short* __restrict__ Am1,
    const float* __restrict__ B0, const float* __restrict__ B1,
    int Mrows, int kchunk, float* __restrict__ outp) {
  __shared__ unsigned short lsB[2][2 * 4 * 256 * 8];  // [buf][split][kq][n256][8k]
  const int tid = threadIdx.x, lane = tid & 63, wid = tid >> 6;
  const int n0 = blockIdx.x * 256, m0 = blockIdx.y * 256;
  const int kbase = blockIdx.z * kchunk;

  const unsigned short *Ah, *Am; const float* B; int koff;
  if (kbase < 2048) { Ah = Ah0; Am = Am0; B = B0; koff = kbase; }
  else              { Ah = Ah1; Am = Am1; B = B1; koff = kbase - 2048; }
  const int nt = kchunk >> 5;

  const int c0 = lane >> 4, l15 = lane & 15;
  const int wm = wid >> 1, wn = wid & 1;

  const unsigned short* ap[4][2];
#pragma unroll
  for (int mf = 0; mf < 4; ++mf) {
    size_t off = (size_t)(m0 + wm * 64 + mf * 16 + l15) * 2048 + koff + c0 * 8;
    ap[mf][0] = Ah + off;
    ap[mf][1] = Am + off;
  }

  const int kq = tid >> 7, nn = tid & 127;
  const float* bptr = B + (size_t)(koff + kq * 8) * 8192 + n0 + nn;
  const int bo0 = kq * 2048 + nn * 8;
  const int bo1 = kq * 2048 + (nn + 128) * 8;
  float bwa[8], bwb[8];
  us8 bs[4];
  auto LOADB = [&]() {
#pragma unroll
    for (int r = 0; r < 8; ++r) {
      bwa[r] = bptr[(size_t)r * 8192];
      bwb[r] = bptr[(size_t)r * 8192 + 128];
    }
    bptr += (size_t)32 * 8192;
  };
  auto SPLITB = [&]() {
#pragma unroll
    for (int r = 0; r < 8; ++r) {
      unsigned short h, m;
      split2(bwa[r], h, m);
      bs[0][r] = h; bs[1][r] = m;
      split2(bwb[r], h, m);
      bs[2][r] = h; bs[3][r] = m;
    }
  };
  auto WRITEB = [&](int buf) {
    *(us8*)&lsB[buf][bo0] = bs[0];
    *(us8*)&lsB[buf][8192 + bo0] = bs[1];
    *(us8*)&lsB[buf][bo1] = bs[2];
    *(us8*)&lsB[buf][8192 + bo1] = bs[3];
  };

  f32x4 acc[4][8];
#pragma unroll
  for (int i = 0; i < 4; ++i)
#pragma unroll
    for (int j = 0; j < 8; ++j) acc[i][j] = (f32x4){0, 0, 0, 0};

  LOADB();
  SPLITB();
  WRITEB(0);
  asm volatile("s_waitcnt lgkmcnt(0)" ::: "memory");
  __builtin_amdgcn_s_barrier();
  __builtin_amdgcn_sched_barrier(0);

  int cur = 0;
  for (int t = 0; t < nt; ++t) {
    bool more = (t + 1 < nt);
    if (more) LOADB();
    bf16x8 a[4][2];
#pragma unroll
    for (int mf = 0; mf < 4; ++mf) {
      a[mf][0] = *(const bf16x8*)ap[mf][0];
      a[mf][1] = *(const bf16x8*)ap[mf][1];
      ap[mf][0] += 32; ap[mf][1] += 32;
    }
#pragma unroll
    for (int nf = 0; nf < 8; ++nf) {
      int ro = c0 * 2048 + (wn * 128 + nf * 16 + l15) * 8;
      bf16x8 b0 = *(const bf16x8*)&lsB[cur][ro];
      bf16x8 b1 = *(const bf16x8*)&lsB[cur][8192 + ro];
#pragma unroll
      for (int mf = 0; mf < 4; ++mf) {
        acc[mf][nf] = __builtin_amdgcn_mfma_f32_16x16x32_bf16(a[mf][0], b0, acc[mf][nf], 0, 0, 0);
        acc[mf][nf] = __builtin_amdgcn_mfma_f32_16x16x32_bf16(a[mf][1], b0, acc[mf][nf], 0, 0, 0);
        acc[mf][nf] = __builtin_amdgcn_mfma_f32_16x16x32_bf16(a[mf][0], b1, acc[mf][nf], 0, 0, 0);
      }
    }
    if (more) {
      SPLITB();
      WRITEB(cur ^ 1);
    }
    asm volatile("s_waitcnt lgkmcnt(0)" ::: "memory");
    __builtin_amdgcn_s_barrier();
    __builtin_amdgcn_sched_barrier(0);
    cur ^= 1;
  }

#pragma unroll
  for (int mf = 0; mf < 4; ++mf)
#pragma unroll
    for (int nf = 0; nf < 8; ++nf)
#pragma unroll
      for (int r = 0; r < 4; ++r) {
        int m = m0 + wm * 64 + mf * 16 + c0 * 4 + r;
        int n = n0 + wn * 128 + nf * 16 + l15;
        outp[((size_t)blockIdx.z * Mrows + m) * 8192 + n] = acc[mf][nf][r];
      }
}

// ---- gates: sums nparts z-partials (+ optional zx0/zx1), all-tanh; czero treats
// c-in as 0 (t=0). Writes h split pair + optional conv2-gather split pair.
__global__ void k_gates(const float* __restrict__ zpart, int nparts,
                        const float* __restrict__ zx0, const float* __restrict__ zx1,
                        const float* __restrict__ bias, float* __restrict__ c, int czero,
                        unsigned short* __restrict__ Hh, unsigned short* __restrict__ Hm,
                        unsigned short* __restrict__ ydh, unsigned short* __restrict__ ydm,
                        int s) {
  int i = blockIdx.x * 256 + threadIdx.x;
  int b = i >> 11, u = i & 2047;
  float g4[4];
#pragma unroll
  for (int gi = 0; gi < 4; ++gi) {
    int n = u + gi * 2048;
    float v = bias[n];
    for (int p = 0; p < nparts; ++p) v += zpart[((size_t)p * 256 + b) * 8192 + n];
    if (zx0) v += zx0[(size_t)b * 8192 + n];
    if (zx1) v += zx1[(size_t)b * 8192 + n];
    g4[gi] = tanhf(v);
  }
  float cold = czero ? 0.f : c[i];
  float cn = g4[1] * cold + g4[0] * g4[2];
  c[i] = cn;
  float h = g4[3] * tanhf(cn);
  unsigned short hh, hm;
  split2(h, hh, hm);
  Hh[i] = hh; Hm[i] = hm;
  if (ydh) {
    size_t a = (size_t)(b * 16 + (u >> 9) * 4 + s) * 512 + (u & 511);
    ydh[a] = hh; ydm[a] = hm;
  }
}

// ---- IN+lrelu after conv1 (sums 2 partials [4096][512]), writes steps split pair
__global__ void k_inorm1(const float* __restrict__ part, const float* __restrict__ gamma,
                         const float* __restrict__ beta,
                         unsigned short* __restrict__ Sh, unsigned short* __restrict__ Sm) {
  int d = blockIdx.y * 256 + threadIdx.x;
  int b = blockIdx.x;
  float v[16], s = 0.f, s2 = 0.f;
#pragma unroll
  for (int p = 0; p < 16; ++p) {
    float xv = part[((size_t)(b * 16 + p)) * 512 + d] +
               part[((size_t)(4096 + b * 16 + p)) * 512 + d];
    v[p] = xv; s += xv; s2 += xv * xv;
  }
  float mean = s * (1.f / 16.f);
  float var = s2 * (1.f / 16.f) - mean * mean;
  float sc = gamma[d] * rsqrtf(var + EPSN);
  float bt = beta[d];
#pragma unroll
  for (int p = 0; p < 16; ++p) {
    int hh = p >> 2, w = p & 3;
    float xn = (v[p] - mean) * sc + bt;
    xn = xn >= 0.f ? xn : 0.2f * xn;
    size_t a = (size_t)(w * 256 + b) * 2048 + hh * 512 + d;
    unsigned short th, tm;
    split2(xn, th, tm);
    Sh[a] = th; Sm[a] = tm;
  }
}

// ---- IN+lrelu after conv2 (single partial [4096][1024]), writes final out
__global__ void k_inorm2(const float* __restrict__ part, const float* __restrict__ gamma,
                         const float* __restrict__ beta, float* __restrict__ out) {
  int o = blockIdx.y * 256 + threadIdx.x;
  int b = blockIdx.x;
  float v[16], s = 0.f, s2 = 0.f;
#pragma unroll
  for (int p = 0; p < 16; ++p) {
    float xv = part[((size_t)(b * 16 + p)) * 1024 + o];
    v[p] = xv; s += xv; s2 += xv * xv;
  }
  float mean = s * (1.f / 16.f);
  float var = s2 * (1.f / 16.f) - mean * mean;
  float sc = gamma[o] * rsqrtf(var + EPSN);
  float bt = beta[o];
#pragma unroll
  for (int p = 0; p < 16; ++p) {
    float xn = (v[p] - mean) * sc + bt;
    xn = xn >= 0.f ? xn : 0.2f * xn;
    out[((size_t)(b * 16 + p)) * 1024 + o] = xn;
  }
}

extern "C" void kernel_launch(void* const* d_in, const int* in_sizes, int n_in,
                              void* d_out, int out_size, void* d_ws, size_t ws_size,
                              hipStream_t stream) {
  (void)in_sizes; (void)n_in; (void)out_size;
  const float* x     = (const float*)d_in[0];
  const float* w1    = (const float*)d_in[1];
  const float* g1    = (const float*)d_in[2];
  const float* b1    = (const float*)d_in[3];
  const float* enc_k = (const float*)d_in[4];
  const float* enc_r = (const float*)d_in[5];
  const float* enc_b = (const float*)d_in[6];
  const float* dec_k = (const float*)d_in[7];
  const float* dec_r = (const float*)d_in[8];
  const float* dec_b = (const float*)d_in[9];
  const float* w2    = (const float*)d_in[10];
  const float* g2    = (const float*)d_in[11];
  const float* b2    = (const float*)d_in[12];
  float* out = (float*)d_out;

  if (ws_size < 176160768ULL) return;  // 168 MiB known-good bound

  // Layout — same regions as r13-r20 (ZX = 2 partials [1024][8192] = 64Mi):
  char* base = (char*)d_ws;
  float* zpart = (float*)base;
  float* ZX    = (float*)(base + (64ull << 20));
  char*  xreg  = base + (128ull << 20);
  unsigned short* xh  = (unsigned short*)xreg;               // [4096][1024]
  unsigned short* xm  = (unsigned short*)(xreg + (8ull << 20));
  unsigned short* ydh = (unsigned short*)xreg;               // [4096][512]
  unsigned short* ydm = (unsigned short*)(xreg + (4ull << 20));
  unsigned short* h1s = (unsigned short*)(xreg + (8ull << 20));
  unsigned short* h2s = (unsigned short*)(xreg + (10ull << 20));
  unsigned short* y0s = (unsigned short*)(xreg + (12ull << 20));
  unsigned short* y1s = (unsigned short*)(xreg + (14ull << 20));
  unsigned short* st2 = (unsigned short*)(base + (144ull << 20));
  float* c1 = (float*)(base + (152ull << 20));
  float* c2 = (float*)(base + (154ull << 20));

  const size_t SP = 1024ull * 2048;   // steps split stride
  const size_t HP = 256ull * 2048;    // h split stride
  unsigned short *sth = st2, *stm = st2 + SP;
  unsigned short *h1h = h1s, *h1m = h1s + HP;
  unsigned short *h2h = h2s, *h2m = h2s + HP;
  unsigned short* ys[2] = {y0s, y1s};

  // conv1 via kgm (128^2): split x ([4096][1024] = [m][k]), 2 k-partials
  k_splitx<<<4096, 256, 0, stream>>>(x, xh, xm, 1048576);
  kgm<<<dim3(4, 32, 2), 256, 0, stream>>>(xh, xm, xh, xm, w1, w1,
                                          1024, 512, 4096, 512, zpart);
  k_inorm1<<<dim3(256, 2), 256, 0, stream>>>(zpart, g1, b1, sth, stm);

  // ZX = steps @ enc_k (all 4 timesteps): BN=256 kernel, grid (32,4,2), 2 partials
  kgm2b<<<dim3(32, 4, 2), 512, 0, stream>>>(sth, stm, sth, stm, enc_k, enc_k,
                                            1024, 1024, ZX);

  // encoder t=0: h1=c1=h2=c2=0 -> layer1 GEMM skipped; layer2 K=2048 only
  k_gates<<<2048, 256, 0, stream>>>(nullptr, 0, ZX, ZX + SP * 4, enc_b, c1, 1,
                                    h1h, h1m, nullptr, nullptr, 0);
  kgm2<<<dim3(64, 1, 2), 512, 0, stream>>>(h1h, h1m, h1h, h1m, enc_k, enc_k,
                                           256, 1024, zpart);
  k_gates<<<2048, 256, 0, stream>>>(zpart, 2, nullptr, nullptr, enc_b, c2, 1,
                                    h2h, h2m, nullptr, nullptr, 0);
  // encoder t=1..3
  for (int t = 1; t < 4; ++t) {
    kgm2<<<dim3(64, 1, 4), 512, 0, stream>>>(h1h, h1m, h1h, h1m, enc_r, enc_r,
                                             256, 512, zpart);
    k_gates<<<2048, 256, 0, stream>>>(zpart, 4, ZX + (size_t)t * 256 * 8192,
                                      ZX + SP * 4 + (size_t)t * 256 * 8192, enc_b, c1, 0,
                                      h1h, h1m, nullptr, nullptr, 0);
    kgm2<<<dim3(64, 1, 4), 512, 0, stream>>>(h1h, h1m, h2h, h2m, enc_k, enc_r,
                                             256, 1024, zpart);
    k_gates<<<2048, 256, 0, stream>>>(zpart, 4, nullptr, nullptr, enc_b, c2, 0,
                                      h2h, h2m, nullptr, nullptr, 0);
  }
  // decoder
  for (int s = 0; s < 4; ++s) {
    const unsigned short *xhh, *xmm, *ph, *pm;
    if (s == 0) {
      xhh = sth + 768 * 2048; xmm = stm + 768 * 2048;
      ph = h2h; pm = h2m;
    } else {
      unsigned short* pr = ys[(s - 1) & 1];
      xhh = pr; xmm = pr + HP;
      ph = pr; pm = pr + HP;
    }
    kgm2<<<dim3(64, 1, 4), 512, 0, stream>>>(xhh, xmm, h1h, h1m, dec_k, dec_r,
                                             256, 1024, zpart);
    k_gates<<<2048, 256, 0, stream>>>(zpart, 4, nullptr, nullptr, dec_b, c1, 0,
                                      h1h, h1m, nullptr, nullptr, 0);
    kgm2<<<dim3(64, 1, 4), 512, 0, stream>>>(h1h, h1m, ph, pm, dec_k, dec_r,
                                             256, 1024, zpart);
    unsigned short* cur = ys[s & 1];
    k_gates<<<2048, 256, 0, stream>>>(zpart, 4, nullptr, nullptr, dec_b, c2, 0,
                                      cur, cur + HP, ydh, ydm, s);
  }

  // conv2 via kgm (128^2): gathered y split pair [4096][512] @ w2[512][1024], 1 partial
  kgm<<<dim3(8, 32, 1), 256, 0, stream>>>(ydh, ydm, ydh, ydm, w2, w2,
                                          512, 1024, 4096, 512, zpart);
  k_inorm2<<<dim3(256, 4), 256, 0, stream>>>(zpart, g2, b2, out);
}

// Round 22
// 1587.575 us; speedup vs baseline: 1.0442x; 1.0442x over previous
//
#include <hip/hip_runtime.h>

#define EPSN 1e-6f

typedef __attribute__((ext_vector_type(4))) float f32x4;
typedef __attribute__((ext_vector_type(8))) __bf16 bf16x8;
typedef __attribute__((ext_vector_type(8))) unsigned short us8;
typedef __attribute__((ext_vector_type(4))) unsigned short us4;
typedef __attribute__((ext_vector_type(4))) float f4v;

__device__ __forceinline__ void async16(const void* g, void* l) {
  __builtin_amdgcn_global_load_lds(
      (const __attribute__((address_space(1))) unsigned int*)g,
      (__attribute__((address_space(3))) unsigned int*)l, 16, 0, 0);
}

// 2-level bf16 split: v ~= h + m with residual <= 2^-18 rel
__device__ __forceinline__ void split2(float v, unsigned short& h, unsigned short& m) {
  __bf16 a = (__bf16)v;  float fa = (float)a;
  __bf16 b = (__bf16)(v - fa);
  h = __builtin_bit_cast(unsigned short, a);
  m = __builtin_bit_cast(unsigned short, b);
}

// ---- x -> split pair (elementwise)
__global__ void k_splitx(const float* __restrict__ in, unsigned short* __restrict__ oh,
                         unsigned short* __restrict__ om, int n4) {
  int i = blockIdx.x * 256 + threadIdx.x;
  if (i < n4) {
    f4v v = ((const f4v*)in)[i];
    us4 h, m;
#pragma unroll
    for (int j = 0; j < 4; ++j) { unsigned short a, b; split2(v[j], a, b); h[j] = a; m[j] = b; }
    ((us4*)oh)[i] = h;
    ((us4*)om)[i] = m;
  }
}

// ==== kgm: 128^2-tile 3-term split GEMM (hh+hm+mh) — convs only (r18-proven) ====
__global__ __launch_bounds__(256, 2) void kgm(
    const unsigned short* __restrict__ Ah0, const unsigned short* __restrict__ Am0,
    const unsigned short* __restrict__ Ah1, const unsigned short* __restrict__ Am1,
    const float* __restrict__ B0, const float* __restrict__ B1,
    int lda, int N, int Mrows, int kchunk, float* __restrict__ outp) {
  __shared__ unsigned short lsA[2][2 * 128 * 32];
  __shared__ unsigned short lsB[2 * 4 * 128 * 8];
  const int tid = threadIdx.x, lane = tid & 63, wid = tid >> 6;
  const int n0 = blockIdx.x * 128, m0 = blockIdx.y * 128;
  const int kbase = blockIdx.z * kchunk;

  const unsigned short *Ah, *Am; const float* B; int koff;
  if (kbase < 2048) { Ah = Ah0; Am = Am0; B = B0; koff = kbase; }
  else              { Ah = Ah1; Am = Am1; B = B1; koff = kbase - 2048; }
  const int nt = kchunk >> 5;

  const unsigned short* asrc[4];
  int adst[4];
#pragma unroll
  for (int j = 0; j < 4; ++j) {
    int idx = j * 256 + tid;
    int s = idx >> 9, rem = idx & 511, row = rem >> 2, slot = idx & 3;
    const unsigned short* base = (s == 0) ? Ah : Am;
    asrc[j] = base + (size_t)(m0 + row) * lda + koff + ((slot ^ ((row >> 1) & 3)) << 3);
    adst[j] = (j * 256 + (tid & ~63)) * 16;
  }
  auto STAGEA = [&](int buf) {
#pragma unroll
    for (int j = 0; j < 4; ++j) {
      async16(asrc[j], (char*)&lsA[buf][0] + adst[j]);
      asrc[j] += 32;
    }
  };

  const int kq = tid >> 6, nn = tid & 63;
  const float* bptr = B + (size_t)(koff + kq * 8) * N + n0 + nn;
  const int bo0 = kq * 1024 + nn * 8;
  const int bo1 = kq * 1024 + (nn + 64) * 8;
  float bwa[8], bwb[8];
  us8 bs[4];
  auto LOADB = [&]() {
#pragma unroll
    for (int r = 0; r < 8; ++r) {
      bwa[r] = bptr[(size_t)r * N];
      bwb[r] = bptr[(size_t)r * N + 64];
    }
    bptr += (size_t)32 * N;
  };
  auto SPLITB = [&]() {
#pragma unroll
    for (int r = 0; r < 8; ++r) {
      unsigned short h, m;
      split2(bwa[r], h, m);
      bs[0][r] = h; bs[1][r] = m;
      split2(bwb[r], h, m);
      bs[2][r] = h; bs[3][r] = m;
    }
  };
  auto WRITEB = [&]() {
    *(us8*)&lsB[bo0] = bs[0];
    *(us8*)&lsB[4096 + bo0] = bs[1];
    *(us8*)&lsB[bo1] = bs[2];
    *(us8*)&lsB[4096 + bo1] = bs[3];
  };

  const int c0 = lane >> 4, l15 = lane & 15;
  const int wm = wid >> 1, wn = wid & 1;
  f32x4 acc[4][4];
#pragma unroll
  for (int i = 0; i < 4; ++i)
#pragma unroll
    for (int j = 0; j < 4; ++j) acc[i][j] = (f32x4){0, 0, 0, 0};

  STAGEA(0);
  LOADB();
  SPLITB();
  int abuf = 0;
  for (int t = 0; t < nt; ++t) {
    __syncthreads();
    WRITEB();
    __syncthreads();
    bool more = (t + 1 < nt);
    if (more) {
      STAGEA(abuf ^ 1);
      LOADB();
    }
    bf16x8 a[4][2];
#pragma unroll
    for (int mf = 0; mf < 4; ++mf) {
      int m = wm * 64 + mf * 16 + l15;
      int ro = m * 32 + ((c0 ^ ((m >> 1) & 3)) << 3);
      a[mf][0] = *(const bf16x8*)&lsA[abuf][ro];
      a[mf][1] = *(const bf16x8*)&lsA[abuf][4096 + ro];
    }
#pragma unroll
    for (int nf = 0; nf < 4; ++nf) {
      int ro = c0 * 1024 + (wn * 64 + nf * 16 + l15) * 8;
      bf16x8 b0 = *(const bf16x8*)&lsB[ro];
      bf16x8 b1 = *(const bf16x8*)&lsB[4096 + ro];
#pragma unroll
      for (int mf = 0; mf < 4; ++mf) {
        acc[mf][nf] = __builtin_amdgcn_mfma_f32_16x16x32_bf16(a[mf][0], b0, acc[mf][nf], 0, 0, 0);
        acc[mf][nf] = __builtin_amdgcn_mfma_f32_16x16x32_bf16(a[mf][1], b0, acc[mf][nf], 0, 0, 0);
        acc[mf][nf] = __builtin_amdgcn_mfma_f32_16x16x32_bf16(a[mf][0], b1, acc[mf][nf], 0, 0, 0);
      }
    }
    if (more) SPLITB();
    abuf ^= 1;
  }

#pragma unroll
  for (int mf = 0; mf < 4; ++mf)
#pragma unroll
    for (int nf = 0; nf < 4; ++nf)
#pragma unroll
      for (int r = 0; r < 4; ++r) {
        int m = m0 + wm * 64 + mf * 16 + c0 * 4 + r;
        int n = n0 + wn * 64 + nf * 16 + l15;
        outp[((size_t)blockIdx.z * Mrows + m) * N + n] = acc[mf][nf][r];
      }
}

// ==== kgm2: 256m x 128n tile — cells. A direct-from-global with REGISTER
// double-buffered one-iteration prefetch (aA/aB, loop unrolled x2, nt must be
// EVEN); B via LDS (2x16KB dbuf, reg->split2->ds_write). One s_barrier/iter,
// drain is lgkmcnt-only. 512 thr / 8 waves, wave tile 64x64, BK=32.
__global__ __launch_bounds__(512, 1) void kgm2(
    const unsigned short* __restrict__ Ah0, const unsigned short* __restrict__ Am0,
    const unsigned short* __restrict__ Ah1, const unsigned short* __restrict__ Am1,
    const float* __restrict__ B0, const float* __restrict__ B1,
    int Mrows, int kchunk, float* __restrict__ outp) {
  __shared__ unsigned short lsB[2][2 * 4 * 128 * 8];  // [buf][split][kq][n128][8k]
  const int tid = threadIdx.x, lane = tid & 63, wid = tid >> 6;
  const int n0 = blockIdx.x * 128, m0 = blockIdx.y * 256;
  const int kbase = blockIdx.z * kchunk;

  const unsigned short *Ah, *Am; const float* B; int koff;
  if (kbase < 2048) { Ah = Ah0; Am = Am0; B = B0; koff = kbase; }
  else              { Ah = Ah1; Am = Am1; B = B1; koff = kbase - 2048; }
  const int nt = kchunk >> 5;  // even for all call sites (16 or 32)

  const int c0 = lane >> 4, l15 = lane & 15;
  const int wm = wid >> 1, wn = wid & 1;

  // A: per-lane fragment pointers; each load = 16 full 64B lines per instr.
  const unsigned short* aph[4];
  const unsigned short* apm[4];
#pragma unroll
  for (int mf = 0; mf < 4; ++mf) {
    size_t off = (size_t)(m0 + wm * 64 + mf * 16 + l15) * 2048 + koff + c0 * 8;
    aph[mf] = Ah + off;
    apm[mf] = Am + off;
  }
  bf16x8 aA[4][2], aB[4][2];
  auto LOADA = [&](bf16x8 (*dst)[2]) {
#pragma unroll
    for (int mf = 0; mf < 4; ++mf) {
      dst[mf][0] = *(const bf16x8*)aph[mf];
      dst[mf][1] = *(const bf16x8*)apm[mf];
      aph[mf] += 32; apm[mf] += 32;
    }
  };

  const int kq = tid >> 7, nn = tid & 127;
  const float* bptr = B + (size_t)(koff + kq * 8) * 8192 + n0 + nn;
  const int bo = kq * 1024 + nn * 8;
  float bw[8];
  us8 bsh, bsm;
  auto LOADB = [&]() {
#pragma unroll
    for (int r = 0; r < 8; ++r) bw[r] = bptr[(size_t)r * 8192];
    bptr += (size_t)32 * 8192;
  };
  auto SPLITB = [&]() {
#pragma unroll
    for (int r = 0; r < 8; ++r) {
      unsigned short h, m;
      split2(bw[r], h, m);
      bsh[r] = h; bsm[r] = m;
    }
  };
  auto WRITEB = [&](int buf) {
    *(us8*)&lsB[buf][bo] = bsh;
    *(us8*)&lsB[buf][4096 + bo] = bsm;
  };

  f32x4 acc[4][4];
#pragma unroll
  for (int i = 0; i < 4; ++i)
#pragma unroll
    for (int j = 0; j < 4; ++j) acc[i][j] = (f32x4){0, 0, 0, 0};

  auto COMPUTE = [&](const bf16x8 (*a)[2], int buf) {
#pragma unroll
    for (int nf = 0; nf < 4; ++nf) {
      int ro = c0 * 1024 + (wn * 64 + nf * 16 + l15) * 8;
      bf16x8 b0 = *(const bf16x8*)&lsB[buf][ro];
      bf16x8 b1 = *(const bf16x8*)&lsB[buf][4096 + ro];
#pragma unroll
      for (int mf = 0; mf < 4; ++mf) {
        acc[mf][nf] = __builtin_amdgcn_mfma_f32_16x16x32_bf16(a[mf][0], b0, acc[mf][nf], 0, 0, 0);
        acc[mf][nf] = __builtin_amdgcn_mfma_f32_16x16x32_bf16(a[mf][1], b0, acc[mf][nf], 0, 0, 0);
        acc[mf][nf] = __builtin_amdgcn_mfma_f32_16x16x32_bf16(a[mf][0], b1, acc[mf][nf], 0, 0, 0);
      }
    }
  };

  // prologue: A(0) regs + B(0) staged
  LOADB();
  LOADA(aA);
  SPLITB();
  WRITEB(0);
  asm volatile("s_waitcnt lgkmcnt(0)" ::: "memory");
  __builtin_amdgcn_s_barrier();
  __builtin_amdgcn_sched_barrier(0);

  int cur = 0;
  for (int t = 0; t < nt; t += 2) {
    // even iter: consume aA, prefetch aB (always another iter since nt even)
    LOADB();
    LOADA(aB);
    COMPUTE(aA, cur);
    SPLITB();
    WRITEB(cur ^ 1);
    asm volatile("s_waitcnt lgkmcnt(0)" ::: "memory");
    __builtin_amdgcn_s_barrier();
    __builtin_amdgcn_sched_barrier(0);
    cur ^= 1;
    // odd iter: consume aB, prefetch aA
    bool more = (t + 2 < nt);
    if (more) {
      LOADB();
      LOADA(aA);
    }
    COMPUTE(aB, cur);
    if (more) {
      SPLITB();
      WRITEB(cur ^ 1);
    }
    asm volatile("s_waitcnt lgkmcnt(0)" ::: "memory");
    __builtin_amdgcn_s_barrier();
    __builtin_amdgcn_sched_barrier(0);
    cur ^= 1;
  }

  // C/D: col = lane&15, row = (lane>>4)*4 + r  [m89-verified]
#pragma unroll
  for (int mf = 0; mf < 4; ++mf)
#pragma unroll
    for (int nf = 0; nf < 4; ++nf)
#pragma unroll
      for (int r = 0; r < 4; ++r) {
        int m = m0 + wm * 64 + mf * 16 + c0 * 4 + r;
        int n = n0 + wn * 64 + nf * 16 + l15;
        outp[((size_t)blockIdx.z * Mrows + m) * 8192 + n] = acc[mf][nf][r];
      }
}

// ==== kgm2b: 256x256 tile, 8 waves, wave tile 64x128, LDS A (r20-proven) — ZX ====
__global__ __launch_bounds__(512, 1) void kgm2b(
    const unsigned short* __restrict__ Ah0, const unsigned short* __restrict__ Am0,
    const unsigned short* __restrict__ Ah1, const unsigned short* __restrict__ Am1,
    const float* __restrict__ B0, const float* __restrict__ B1,
    int Mrows, int kchunk, float* __restrict__ outp) {
  __shared__ unsigned short lsA[2][2 * 256 * 32];
  __shared__ unsigned short lsB[2][2 * 4 * 256 * 8];
  const int tid = threadIdx.x, lane = tid & 63, wid = tid >> 6;
  const int n0 = blockIdx.x * 256, m0 = blockIdx.y * 256;
  const int kbase = blockIdx.z * kchunk;

  const unsigned short *Ah, *Am; const float* B; int koff;
  if (kbase < 2048) { Ah = Ah0; Am = Am0; B = B0; koff = kbase; }
  else              { Ah = Ah1; Am = Am1; B = B1; koff = kbase - 2048; }
  const int nt = kchunk >> 5;

  const unsigned short* asrc[4];
  int adst[4];
#pragma unroll
  for (int j = 0; j < 4; ++j) {
    int idx = j * 512 + tid;
    int s = idx >> 10, rem = idx & 1023, row = rem >> 2, slot = idx & 3;
    const unsigned short* base = (s == 0) ? Ah : Am;
    asrc[j] = base + (size_t)(m0 + row) * 2048 + koff + ((slot ^ ((row >> 1) & 3)) << 3);
    adst[j] = (j * 512 + (tid & ~63)) * 16;
  }
  auto STAGEA = [&](int buf) {
#pragma unroll
    for (int j = 0; j < 4; ++j) {
      async16(asrc[j], (char*)&lsA[buf][0] + adst[j]);
      asrc[j] += 32;
    }
  };

  const int kq = tid >> 7, nn = tid & 127;
  const float* bptr = B + (size_t)(koff + kq * 8) * 8192 + n0 + nn;
  const int bo0 = kq * 2048 + nn * 8;
  const int bo1 = kq * 2048 + (nn + 128) * 8;
  float bwa[8], bwb[8];
  us8 bs[4];
  auto LOADB = [&]() {
#pragma unroll
    for (int r = 0; r < 8; ++r) {
      bwa[r] = bptr[(size_t)r * 8192];
      bwb[r] = bptr[(size_t)r * 8192 + 128];
    }
    bptr += (size_t)32 * 8192;
  };
  auto SPLITB = [&]() {
#pragma unroll
    for (int r = 0; r < 8; ++r) {
      unsigned short h, m;
      split2(bwa[r], h, m);
      bs[0][r] = h; bs[1][r] = m;
      split2(bwb[r], h, m);
      bs[2][r] = h; bs[3][r] = m;
    }
  };
  auto WRITEB = [&](int buf) {
    *(us8*)&lsB[buf][bo0] = bs[0];
    *(us8*)&lsB[buf][8192 + bo0] = bs[1];
    *(us8*)&lsB[buf][bo1] = bs[2];
    *(us8*)&lsB[buf][8192 + bo1] = bs[3];
  };

  const int c0 = lane >> 4, l15 = lane & 15;
  const int wm = wid >> 1, wn = wid & 1;
  f32x4 acc[4][8];
#pragma unroll
  for (int i = 0; i < 4; ++i)
#pragma unroll
    for (int j = 0; j < 8; ++j) acc[i][j] = (f32x4){0, 0, 0, 0};

  LOADB();
  STAGEA(0);
  SPLITB();
  WRITEB(0);
  asm volatile("s_waitcnt vmcnt(0) lgkmcnt(0)" ::: "memory");
  __builtin_amdgcn_s_barrier();
  __builtin_amdgcn_sched_barrier(0);

  int cur = 0;
  for (int t = 0; t < nt; ++t) {
    bool more = (t + 1 < nt);
    if (more) {
      LOADB();
      STAGEA(cur ^ 1);
    }
    bf16x8 a[4][2];
#pragma unroll
    for (int mf = 0; mf < 4; ++mf) {
      int m = wm * 64 + mf * 16 + l15;
      int ro = m * 32 + ((c0 ^ ((m >> 1) & 3)) << 3);
      a[mf][0] = *(const bf16x8*)&lsA[cur][ro];
      a[mf][1] = *(const bf16x8*)&lsA[cur][8192 + ro];
    }
#pragma unroll
    for (int nf = 0; nf < 8; ++nf) {
      int ro = c0 * 2048 + (wn * 128 + nf * 16 + l15) * 8;
      bf16x8 b0 = *(const bf16x8*)&lsB[cur][ro];
      bf16x8 b1 = *(const bf16x8*)&lsB[cur][8192 + ro];
#pragma unroll
      for (int mf = 0; mf < 4; ++mf) {
        acc[mf][nf] = __builtin_amdgcn_mfma_f32_16x16x32_bf16(a[mf][0], b0, acc[mf][nf], 0, 0, 0);
        acc[mf][nf] = __builtin_amdgcn_mfma_f32_16x16x32_bf16(a[mf][1], b0, acc[mf][nf], 0, 0, 0);
        acc[mf][nf] = __builtin_amdgcn_mfma_f32_16x16x32_bf16(a[mf][0], b1, acc[mf][nf], 0, 0, 0);
      }
    }
    if (more) {
      SPLITB();
      WRITEB(cur ^ 1);
    }
    asm volatile("s_waitcnt vmcnt(0) lgkmcnt(0)" ::: "memory");
    __builtin_amdgcn_s_barrier();
    __builtin_amdgcn_sched_barrier(0);
    cur ^= 1;
  }

#pragma unroll
  for (int mf = 0; mf < 4; ++mf)
#pragma unroll
    for (int nf = 0; nf < 8; ++nf)
#pragma unroll
      for (int r = 0; r < 4; ++r) {
        int m = m0 + wm * 64 + mf * 16 + c0 * 4 + r;
        int n = n0 + wn * 128 + nf * 16 + l15;
        outp[((size_t)blockIdx.z * Mrows + m) * 8192 + n] = acc[mf][nf][r];
      }
}

// ---- gates: sums nparts z-partials (+ optional zx0/zx1), all-tanh; czero treats
// c-in as 0 (t=0). Writes h split pair + optional conv2-gather split pair.
__global__ void k_gates(const float* __restrict__ zpart, int nparts,
                        const float* __restrict__ zx0, const float* __restrict__ zx1,
                        const float* __restrict__ bias, float* __restrict__ c, int czero,
                        unsigned short* __restrict__ Hh, unsigned short* __restrict__ Hm,
                        unsigned short* __restrict__ ydh, unsigned short* __restrict__ ydm,
                        int s) {
  int i = blockIdx.x * 256 + threadIdx.x;
  int b = i >> 11, u = i & 2047;
  float g4[4];
#pragma unroll
  for (int gi = 0; gi < 4; ++gi) {
    int n = u + gi * 2048;
    float v = bias[n];
    for (int p = 0; p < nparts; ++p) v += zpart[((size_t)p * 256 + b) * 8192 + n];
    if (zx0) v += zx0[(size_t)b * 8192 + n];
    if (zx1) v += zx1[(size_t)b * 8192 + n];
    g4[gi] = tanhf(v);
  }
  float cold = czero ? 0.f : c[i];
  float cn = g4[1] * cold + g4[0] * g4[2];
  c[i] = cn;
  float h = g4[3] * tanhf(cn);
  unsigned short hh, hm;
  split2(h, hh, hm);
  Hh[i] = hh; Hm[i] = hm;
  if (ydh) {
    size_t a = (size_t)(b * 16 + (u >> 9) * 4 + s) * 512 + (u & 511);
    ydh[a] = hh; ydm[a] = hm;
  }
}

// ---- IN+lrelu after conv1 (sums 2 partials [4096][512]), writes steps split pair
__global__ void k_inorm1(const float* __restrict__ part, const float* __restrict__ gamma,
                         const float* __restrict__ beta,
                         unsigned short* __restrict__ Sh, unsigned short* __restrict__ Sm) {
  int d = blockIdx.y * 256 + threadIdx.x;
  int b = blockIdx.x;
  float v[16], s = 0.f, s2 = 0.f;
#pragma unroll
  for (int p = 0; p < 16; ++p) {
    float xv = part[((size_t)(b * 16 + p)) * 512 + d] +
               part[((size_t)(4096 + b * 16 + p)) * 512 + d];
    v[p] = xv; s += xv; s2 += xv * xv;
  }
  float mean = s * (1.f / 16.f);
  float var = s2 * (1.f / 16.f) - mean * mean;
  float sc = gamma[d] * rsqrtf(var + EPSN);
  float bt = beta[d];
#pragma unroll
  for (int p = 0; p < 16; ++p) {
    int hh = p >> 2, w = p & 3;
    float xn = (v[p] - mean) * sc + bt;
    xn = xn >= 0.f ? xn : 0.2f * xn;
    size_t a = (size_t)(w * 256 + b) * 2048 + hh * 512 + d;
    unsigned short th, tm;
    split2(xn, th, tm);
    Sh[a] = th; Sm[a] = tm;
  }
}

// ---- IN+lrelu after conv2 (single partial [4096][1024]), writes final out
__global__ void k_inorm2(const float* __restrict__ part, const float* __restrict__ gamma,
                         const float* __restrict__ beta, float* __restrict__ out) {
  int o = blockIdx.y * 256 + threadIdx.x;
  int b = blockIdx.x;
  float v[16], s = 0.f, s2 = 0.f;
#pragma unroll
  for (int p = 0; p < 16; ++p) {
    float xv = part[((size_t)(b * 16 + p)) * 1024 + o];
    v[p] = xv; s += xv; s2 += xv * xv;
  }
  float mean = s * (1.f / 16.f);
  float var = s2 * (1.f / 16.f) - mean * mean;
  float sc = gamma[o] * rsqrtf(var + EPSN);
  float bt = beta[o];
#pragma unroll
  for (int p = 0; p < 16; ++p) {
    float xn = (v[p] - mean) * sc + bt;
    xn = xn >= 0.f ? xn : 0.2f * xn;
    out[((size_t)(b * 16 + p)) * 1024 + o] = xn;
  }
}

extern "C" void kernel_launch(void* const* d_in, const int* in_sizes, int n_in,
                              void* d_out, int out_size, void* d_ws, size_t ws_size,
                              hipStream_t stream) {
  (void)in_sizes; (void)n_in; (void)out_size;
  const float* x     = (const float*)d_in[0];
  const float* w1    = (const float*)d_in[1];
  const float* g1    = (const float*)d_in[2];
  const float* b1    = (const float*)d_in[3];
  const float* enc_k = (const float*)d_in[4];
  const float* enc_r = (const float*)d_in[5];
  const float* enc_b = (const float*)d_in[6];
  const float* dec_k = (const float*)d_in[7];
  const float* dec_r = (const float*)d_in[8];
  const float* dec_b = (const float*)d_in[9];
  const float* w2    = (const float*)d_in[10];
  const float* g2    = (const float*)d_in[11];
  const float* b2    = (const float*)d_in[12];
  float* out = (float*)d_out;

  if (ws_size < 176160768ULL) return;  // 168 MiB known-good bound

  // Layout — same regions as r13-r20 (ZX = 2 partials [1024][8192] = 64Mi):
  char* base = (char*)d_ws;
  float* zpart = (float*)base;
  float* ZX    = (float*)(base + (64ull << 20));
  char*  xreg  = base + (128ull << 20);
  unsigned short* xh  = (unsigned short*)xreg;               // [4096][1024]
  unsigned short* xm  = (unsigned short*)(xreg + (8ull << 20));
  unsigned short* ydh = (unsigned short*)xreg;               // [4096][512]
  unsigned short* ydm = (unsigned short*)(xreg + (4ull << 20));
  unsigned short* h1s = (unsigned short*)(xreg + (8ull << 20));
  unsigned short* h2s = (unsigned short*)(xreg + (10ull << 20));
  unsigned short* y0s = (unsigned short*)(xreg + (12ull << 20));
  unsigned short* y1s = (unsigned short*)(xreg + (14ull << 20));
  unsigned short* st2 = (unsigned short*)(base + (144ull << 20));
  float* c1 = (float*)(base + (152ull << 20));
  float* c2 = (float*)(base + (154ull << 20));

  const size_t SP = 1024ull * 2048;   // steps split stride
  const size_t HP = 256ull * 2048;    // h split stride
  unsigned short *sth = st2, *stm = st2 + SP;
  unsigned short *h1h = h1s, *h1m = h1s + HP;
  unsigned short *h2h = h2s, *h2m = h2s + HP;
  unsigned short* ys[2] = {y0s, y1s};

  // conv1 via kgm (128^2): split x ([4096][1024] = [m][k]), 2 k-partials
  k_splitx<<<4096, 256, 0, stream>>>(x, xh, xm, 1048576);
  kgm<<<dim3(4, 32, 2), 256, 0, stream>>>(xh, xm, xh, xm, w1, w1,
                                          1024, 512, 4096, 512, zpart);
  k_inorm1<<<dim3(256, 2), 256, 0, stream>>>(zpart, g1, b1, sth, stm);

  // ZX = steps @ enc_k (all 4 timesteps): BN=256 kernel, grid (32,4,2), 2 partials
  kgm2b<<<dim3(32, 4, 2), 512, 0, stream>>>(sth, stm, sth, stm, enc_k, enc_k,
                                            1024, 1024, ZX);

  // encoder t=0: h1=c1=h2=c2=0 -> layer1 GEMM skipped; layer2 K=2048 only
  k_gates<<<2048, 256, 0, stream>>>(nullptr, 0, ZX, ZX + SP * 4, enc_b, c1, 1,
                                    h1h, h1m, nullptr, nullptr, 0);
  kgm2<<<dim3(64, 1, 2), 512, 0, stream>>>(h1h, h1m, h1h, h1m, enc_k, enc_k,
                                           256, 1024, zpart);
  k_gates<<<2048, 256, 0, stream>>>(zpart, 2, nullptr, nullptr, enc_b, c2, 1,
                                    h2h, h2m, nullptr, nullptr, 0);
  // encoder t=1..3
  for (int t = 1; t < 4; ++t) {
    kgm2<<<dim3(64, 1, 4), 512, 0, stream>>>(h1h, h1m, h1h, h1m, enc_r, enc_r,
                                             256, 512, zpart);
    k_gates<<<2048, 256, 0, stream>>>(zpart, 4, ZX + (size_t)t * 256 * 8192,
                                      ZX + SP * 4 + (size_t)t * 256 * 8192, enc_b, c1, 0,
                                      h1h, h1m, nullptr, nullptr, 0);
    kgm2<<<dim3(64, 1, 4), 512, 0, stream>>>(h1h, h1m, h2h, h2m, enc_k, enc_r,
                                             256, 1024, zpart);
    k_gates<<<2048, 256, 0, stream>>>(zpart, 4, nullptr, nullptr, enc_b, c2, 0,
                                      h2h, h2m, nullptr, nullptr, 0);
  }
  // decoder
  for (int s = 0; s < 4; ++s) {
    const unsigned short *xhh, *xmm, *ph, *pm;
    if (s == 0) {
      xhh = sth + 768 * 2048; xmm = stm + 768 * 2048;
      ph = h2h; pm = h2m;
    } else {
      unsigned short* pr = ys[(s - 1) & 1];
      xhh = pr; xmm = pr + HP;
      ph = pr; pm = pr + HP;
    }
    kgm2<<<dim3(64, 1, 4), 512, 0, stream>>>(xhh, xmm, h1h, h1m, dec_k, dec_r,
                                             256, 1024, zpart);
    k_gates<<<2048, 256, 0, stream>>>(zpart, 4, nullptr, nullptr, dec_b, c1, 0,
                                      h1h, h1m, nullptr, nullptr, 0);
    kgm2<<<dim3(64, 1, 4), 512, 0, stream>>>(h1h, h1m, ph, pm, dec_k, dec_r,
                                             256, 1024, zpart);
    unsigned short* cur = ys[s & 1];
    k_gates<<<2048, 256, 0, stream>>>(zpart, 4, nullptr, nullptr, dec_b, c2, 0,
                                      cur, cur + HP, ydh, ydm, s);
  }

  // conv2 via kgm (128^2): gathered y split pair [4096][512] @ w2[512][1024], 1 partial
  kgm<<<dim3(8, 32, 1), 256, 0, stream>>>(ydh, ydm, ydh, ydm, w2, w2,
                                          512, 1024, 4096, 512, zpart);
  k_inorm2<<<dim3(256, 4), 256, 0, stream>>>(zpart, g2, b2, out);
}

// Round 23
// 1140.122 us; speedup vs baseline: 1.4541x; 1.3925x over previous
//
#include <hip/hip_runtime.h>

#define EPSN 1e-6f

typedef __attribute__((ext_vector_type(4))) float f32x4;
typedef __attribute__((ext_vector_type(8))) __bf16 bf16x8;
typedef __attribute__((ext_vector_type(8))) unsigned short us8;
typedef __attribute__((ext_vector_type(4))) unsigned short us4;
typedef __attribute__((ext_vector_type(4))) float f4v;

__device__ __forceinline__ void async16(const void* g, void* l) {
  __builtin_amdgcn_global_load_lds(
      (const __attribute__((address_space(1))) unsigned int*)g,
      (__attribute__((address_space(3))) unsigned int*)l, 16, 0, 0);
}

// 2-level bf16 split: v ~= h + m with residual <= 2^-18 rel
__device__ __forceinline__ void split2(float v, unsigned short& h, unsigned short& m) {
  __bf16 a = (__bf16)v;  float fa = (float)a;
  __bf16 b = (__bf16)(v - fa);
  h = __builtin_bit_cast(unsigned short, a);
  m = __builtin_bit_cast(unsigned short, b);
}

// ---- x -> split pair (elementwise)
__global__ void k_splitx(const float* __restrict__ in, unsigned short* __restrict__ oh,
                         unsigned short* __restrict__ om, int n4) {
  int i = blockIdx.x * 256 + threadIdx.x;
  if (i < n4) {
    f4v v = ((const f4v*)in)[i];
    us4 h, m;
#pragma unroll
    for (int j = 0; j < 4; ++j) { unsigned short a, b; split2(v[j], a, b); h[j] = a; m[j] = b; }
    ((us4*)oh)[i] = h;
    ((us4*)om)[i] = m;
  }
}

// ==== kgm: 128^2-tile 3-term split GEMM (hh+hm+mh) — convs only (r18-proven) ====
__global__ __launch_bounds__(256, 2) void kgm(
    const unsigned short* __restrict__ Ah0, const unsigned short* __restrict__ Am0,
    const unsigned short* __restrict__ Ah1, const unsigned short* __restrict__ Am1,
    const float* __restrict__ B0, const float* __restrict__ B1,
    int lda, int N, int Mrows, int kchunk, float* __restrict__ outp) {
  __shared__ unsigned short lsA[2][2 * 128 * 32];
  __shared__ unsigned short lsB[2 * 4 * 128 * 8];
  const int tid = threadIdx.x, lane = tid & 63, wid = tid >> 6;
  const int n0 = blockIdx.x * 128, m0 = blockIdx.y * 128;
  const int kbase = blockIdx.z * kchunk;

  const unsigned short *Ah, *Am; const float* B; int koff;
  if (kbase < 2048) { Ah = Ah0; Am = Am0; B = B0; koff = kbase; }
  else              { Ah = Ah1; Am = Am1; B = B1; koff = kbase - 2048; }
  const int nt = kchunk >> 5;

  const unsigned short* asrc[4];
  int adst[4];
#pragma unroll
  for (int j = 0; j < 4; ++j) {
    int idx = j * 256 + tid;
    int s = idx >> 9, rem = idx & 511, row = rem >> 2, slot = idx & 3;
    const unsigned short* base = (s == 0) ? Ah : Am;
    asrc[j] = base + (size_t)(m0 + row) * lda + koff + ((slot ^ ((row >> 1) & 3)) << 3);
    adst[j] = (j * 256 + (tid & ~63)) * 16;
  }
  auto STAGEA = [&](int buf) {
#pragma unroll
    for (int j = 0; j < 4; ++j) {
      async16(asrc[j], (char*)&lsA[buf][0] + adst[j]);
      asrc[j] += 32;
    }
  };

  const int kq = tid >> 6, nn = tid & 63;
  const float* bptr = B + (size_t)(koff + kq * 8) * N + n0 + nn;
  const int bo0 = kq * 1024 + nn * 8;
  const int bo1 = kq * 1024 + (nn + 64) * 8;
  float bwa[8], bwb[8];
  us8 bs[4];
  auto LOADB = [&]() {
#pragma unroll
    for (int r = 0; r < 8; ++r) {
      bwa[r] = bptr[(size_t)r * N];
      bwb[r] = bptr[(size_t)r * N + 64];
    }
    bptr += (size_t)32 * N;
  };
  auto SPLITB = [&]() {
#pragma unroll
    for (int r = 0; r < 8; ++r) {
      unsigned short h, m;
      split2(bwa[r], h, m);
      bs[0][r] = h; bs[1][r] = m;
      split2(bwb[r], h, m);
      bs[2][r] = h; bs[3][r] = m;
    }
  };
  auto WRITEB = [&]() {
    *(us8*)&lsB[bo0] = bs[0];
    *(us8*)&lsB[4096 + bo0] = bs[1];
    *(us8*)&lsB[bo1] = bs[2];
    *(us8*)&lsB[4096 + bo1] = bs[3];
  };

  const int c0 = lane >> 4, l15 = lane & 15;
  const int wm = wid >> 1, wn = wid & 1;
  f32x4 acc[4][4];
#pragma unroll
  for (int i = 0; i < 4; ++i)
#pragma unroll
    for (int j = 0; j < 4; ++j) acc[i][j] = (f32x4){0, 0, 0, 0};

  STAGEA(0);
  LOADB();
  SPLITB();
  int abuf = 0;
  for (int t = 0; t < nt; ++t) {
    __syncthreads();
    WRITEB();
    __syncthreads();
    bool more = (t + 1 < nt);
    if (more) {
      STAGEA(abuf ^ 1);
      LOADB();
    }
    bf16x8 a[4][2];
#pragma unroll
    for (int mf = 0; mf < 4; ++mf) {
      int m = wm * 64 + mf * 16 + l15;
      int ro = m * 32 + ((c0 ^ ((m >> 1) & 3)) << 3);
      a[mf][0] = *(const bf16x8*)&lsA[abuf][ro];
      a[mf][1] = *(const bf16x8*)&lsA[abuf][4096 + ro];
    }
#pragma unroll
    for (int nf = 0; nf < 4; ++nf) {
      int ro = c0 * 1024 + (wn * 64 + nf * 16 + l15) * 8;
      bf16x8 b0 = *(const bf16x8*)&lsB[ro];
      bf16x8 b1 = *(const bf16x8*)&lsB[4096 + ro];
#pragma unroll
      for (int mf = 0; mf < 4; ++mf) {
        acc[mf][nf] = __builtin_amdgcn_mfma_f32_16x16x32_bf16(a[mf][0], b0, acc[mf][nf], 0, 0, 0);
        acc[mf][nf] = __builtin_amdgcn_mfma_f32_16x16x32_bf16(a[mf][1], b0, acc[mf][nf], 0, 0, 0);
        acc[mf][nf] = __builtin_amdgcn_mfma_f32_16x16x32_bf16(a[mf][0], b1, acc[mf][nf], 0, 0, 0);
      }
    }
    if (more) SPLITB();
    abuf ^= 1;
  }

#pragma unroll
  for (int mf = 0; mf < 4; ++mf)
#pragma unroll
    for (int nf = 0; nf < 4; ++nf)
#pragma unroll
      for (int r = 0; r < 4; ++r) {
        int m = m0 + wm * 64 + mf * 16 + c0 * 4 + r;
        int n = n0 + wn * 64 + nf * 16 + l15;
        outp[((size_t)blockIdx.z * Mrows + m) * N + n] = acc[mf][nf][r];
      }
}

// ==== kgm2: 256m x 128n tile — cells (r20 base + cross-barrier B prefetch) ====
// Per iter: STAGEA(t+1) -> COMPUTE(t) -> SPLITB/WRITEB(t+1) -> vmcnt(0) drain ->
// issue LOADB(t+2) (in flight across barrier + next compute) -> s_barrier.
__global__ __launch_bounds__(512, 1) void kgm2(
    const unsigned short* __restrict__ Ah0, const unsigned short* __restrict__ Am0,
    const unsigned short* __restrict__ Ah1, const unsigned short* __restrict__ Am1,
    const float* __restrict__ B0, const float* __restrict__ B1,
    int Mrows, int kchunk, float* __restrict__ outp) {
  __shared__ unsigned short lsA[2][2 * 256 * 32];
  __shared__ unsigned short lsB[2][2 * 4 * 128 * 8];
  const int tid = threadIdx.x, lane = tid & 63, wid = tid >> 6;
  const int n0 = blockIdx.x * 128, m0 = blockIdx.y * 256;
  const int kbase = blockIdx.z * kchunk;

  const unsigned short *Ah, *Am; const float* B; int koff;
  if (kbase < 2048) { Ah = Ah0; Am = Am0; B = B0; koff = kbase; }
  else              { Ah = Ah1; Am = Am1; B = B1; koff = kbase - 2048; }
  const int nt = kchunk >> 5;

  const unsigned short* asrc[4];
  int adst[4];
#pragma unroll
  for (int j = 0; j < 4; ++j) {
    int idx = j * 512 + tid;
    int s = idx >> 10, rem = idx & 1023, row = rem >> 2, slot = idx & 3;
    const unsigned short* base = (s == 0) ? Ah : Am;
    asrc[j] = base + (size_t)(m0 + row) * 2048 + koff + ((slot ^ ((row >> 1) & 3)) << 3);
    adst[j] = (j * 512 + (tid & ~63)) * 16;
  }
  auto STAGEA = [&](int buf) {
#pragma unroll
    for (int j = 0; j < 4; ++j) {
      async16(asrc[j], (char*)&lsA[buf][0] + adst[j]);
      asrc[j] += 32;
    }
  };

  const int kq = tid >> 7, nn = tid & 127;
  const float* bptr = B + (size_t)(koff + kq * 8) * 8192 + n0 + nn;
  const int bo = kq * 1024 + nn * 8;
  float bw[8];
  us8 bsh, bsm;
  auto LOADB = [&]() {
#pragma unroll
    for (int r = 0; r < 8; ++r) bw[r] = bptr[(size_t)r * 8192];
    bptr += (size_t)32 * 8192;
  };
  auto SPLITB = [&]() {
#pragma unroll
    for (int r = 0; r < 8; ++r) {
      unsigned short h, m;
      split2(bw[r], h, m);
      bsh[r] = h; bsm[r] = m;
    }
  };
  auto WRITEB = [&](int buf) {
    *(us8*)&lsB[buf][bo] = bsh;
    *(us8*)&lsB[buf][4096 + bo] = bsm;
  };

  const int c0 = lane >> 4, l15 = lane & 15;
  const int wm = wid >> 1, wn = wid & 1;
  f32x4 acc[4][4];
#pragma unroll
  for (int i = 0; i < 4; ++i)
#pragma unroll
    for (int j = 0; j < 4; ++j) acc[i][j] = (f32x4){0, 0, 0, 0};

  // prologue: B(0)->lsB[0], A(0) DMA; B(1) issued after drain (in flight over barrier)
  LOADB();
  STAGEA(0);
  SPLITB();
  WRITEB(0);
  asm volatile("s_waitcnt vmcnt(0) lgkmcnt(0)" ::: "memory");
  LOADB();  // B(1)
  __builtin_amdgcn_sched_barrier(0);
  __builtin_amdgcn_s_barrier();
  __builtin_amdgcn_sched_barrier(0);

  int cur = 0;
  for (int t = 0; t < nt; ++t) {
    bool more = (t + 1 < nt);
    if (more) STAGEA(cur ^ 1);  // A(t+1) DMA; drained at this iter's vmcnt(0)
    bf16x8 a[4][2];
#pragma unroll
    for (int mf = 0; mf < 4; ++mf) {
      int m = wm * 64 + mf * 16 + l15;
      int ro = m * 32 + ((c0 ^ ((m >> 1) & 3)) << 3);
      a[mf][0] = *(const bf16x8*)&lsA[cur][ro];
      a[mf][1] = *(const bf16x8*)&lsA[cur][8192 + ro];
    }
#pragma unroll
    for (int nf = 0; nf < 4; ++nf) {
      int ro = c0 * 1024 + (wn * 64 + nf * 16 + l15) * 8;
      bf16x8 b0 = *(const bf16x8*)&lsB[cur][ro];
      bf16x8 b1 = *(const bf16x8*)&lsB[cur][4096 + ro];
#pragma unroll
      for (int mf = 0; mf < 4; ++mf) {
        acc[mf][nf] = __builtin_amdgcn_mfma_f32_16x16x32_bf16(a[mf][0], b0, acc[mf][nf], 0, 0, 0);
        acc[mf][nf] = __builtin_amdgcn_mfma_f32_16x16x32_bf16(a[mf][1], b0, acc[mf][nf], 0, 0, 0);
        acc[mf][nf] = __builtin_amdgcn_mfma_f32_16x16x32_bf16(a[mf][0], b1, acc[mf][nf], 0, 0, 0);
      }
    }
    if (more) {
      SPLITB();          // bw = B(t+1), loaded last iter: cover = barrier + compute
      WRITEB(cur ^ 1);
    }
    asm volatile("s_waitcnt vmcnt(0) lgkmcnt(0)" ::: "memory");  // drain A DMA + ds_writes
    if (t + 2 < nt) LOADB();  // B(t+2): issued post-drain, rides across the barrier
    __builtin_amdgcn_sched_barrier(0);
    __builtin_amdgcn_s_barrier();
    __builtin_amdgcn_sched_barrier(0);
    cur ^= 1;
  }

  // C/D: col = lane&15, row = (lane>>4)*4 + r  [m89-verified]
#pragma unroll
  for (int mf = 0; mf < 4; ++mf)
#pragma unroll
    for (int nf = 0; nf < 4; ++nf)
#pragma unroll
      for (int r = 0; r < 4; ++r) {
        int m = m0 + wm * 64 + mf * 16 + c0 * 4 + r;
        int n = n0 + wn * 64 + nf * 16 + l15;
        outp[((size_t)blockIdx.z * Mrows + m) * 8192 + n] = acc[mf][nf][r];
      }
}

// ==== kgm2b: 256x256 tile, wave tile 64x128 — ZX (r20 base + cross-barrier B prefetch) ====
__global__ __launch_bounds__(512, 1) void kgm2b(
    const unsigned short* __restrict__ Ah0, const unsigned short* __restrict__ Am0,
    const unsigned short* __restrict__ Ah1, const unsigned short* __restrict__ Am1,
    const float* __restrict__ B0, const float* __restrict__ B1,
    int Mrows, int kchunk, float* __restrict__ outp) {
  __shared__ unsigned short lsA[2][2 * 256 * 32];
  __shared__ unsigned short lsB[2][2 * 4 * 256 * 8];
  const int tid = threadIdx.x, lane = tid & 63, wid = tid >> 6;
  const int n0 = blockIdx.x * 256, m0 = blockIdx.y * 256;
  const int kbase = blockIdx.z * kchunk;

  const unsigned short *Ah, *Am; const float* B; int koff;
  if (kbase < 2048) { Ah = Ah0; Am = Am0; B = B0; koff = kbase; }
  else              { Ah = Ah1; Am = Am1; B = B1; koff = kbase - 2048; }
  const int nt = kchunk >> 5;

  const unsigned short* asrc[4];
  int adst[4];
#pragma unroll
  for (int j = 0; j < 4; ++j) {
    int idx = j * 512 + tid;
    int s = idx >> 10, rem = idx & 1023, row = rem >> 2, slot = idx & 3;
    const unsigned short* base = (s == 0) ? Ah : Am;
    asrc[j] = base + (size_t)(m0 + row) * 2048 + koff + ((slot ^ ((row >> 1) & 3)) << 3);
    adst[j] = (j * 512 + (tid & ~63)) * 16;
  }
  auto STAGEA = [&](int buf) {
#pragma unroll
    for (int j = 0; j < 4; ++j) {
      async16(asrc[j], (char*)&lsA[buf][0] + adst[j]);
      asrc[j] += 32;
    }
  };

  const int kq = tid >> 7, nn = tid & 127;
  const float* bptr = B + (size_t)(koff + kq * 8) * 8192 + n0 + nn;
  const int bo0 = kq * 2048 + nn * 8;
  const int bo1 = kq * 2048 + (nn + 128) * 8;
  float bwa[8], bwb[8];
  us8 bs[4];
  auto LOADB = [&]() {
#pragma unroll
    for (int r = 0; r < 8; ++r) {
      bwa[r] = bptr[(size_t)r * 8192];
      bwb[r] = bptr[(size_t)r * 8192 + 128];
    }
    bptr += (size_t)32 * 8192;
  };
  auto SPLITB = [&]() {
#pragma unroll
    for (int r = 0; r < 8; ++r) {
      unsigned short h, m;
      split2(bwa[r], h, m);
      bs[0][r] = h; bs[1][r] = m;
      split2(bwb[r], h, m);
      bs[2][r] = h; bs[3][r] = m;
    }
  };
  auto WRITEB = [&](int buf) {
    *(us8*)&lsB[buf][bo0] = bs[0];
    *(us8*)&lsB[buf][8192 + bo0] = bs[1];
    *(us8*)&lsB[buf][bo1] = bs[2];
    *(us8*)&lsB[buf][8192 + bo1] = bs[3];
  };

  const int c0 = lane >> 4, l15 = lane & 15;
  const int wm = wid >> 1, wn = wid & 1;
  f32x4 acc[4][8];
#pragma unroll
  for (int i = 0; i < 4; ++i)
#pragma unroll
    for (int j = 0; j < 8; ++j) acc[i][j] = (f32x4){0, 0, 0, 0};

  LOADB();
  STAGEA(0);
  SPLITB();
  WRITEB(0);
  asm volatile("s_waitcnt vmcnt(0) lgkmcnt(0)" ::: "memory");
  LOADB();  // B(1) rides across the barrier
  __builtin_amdgcn_sched_barrier(0);
  __builtin_amdgcn_s_barrier();
  __builtin_amdgcn_sched_barrier(0);

  int cur = 0;
  for (int t = 0; t < nt; ++t) {
    bool more = (t + 1 < nt);
    if (more) STAGEA(cur ^ 1);
    bf16x8 a[4][2];
#pragma unroll
    for (int mf = 0; mf < 4; ++mf) {
      int m = wm * 64 + mf * 16 + l15;
      int ro = m * 32 + ((c0 ^ ((m >> 1) & 3)) << 3);
      a[mf][0] = *(const bf16x8*)&lsA[cur][ro];
      a[mf][1] = *(const bf16x8*)&lsA[cur][8192 + ro];
    }
#pragma unroll
    for (int nf = 0; nf < 8; ++nf) {
      int ro = c0 * 2048 + (wn * 128 + nf * 16 + l15) * 8;
      bf16x8 b0 = *(const bf16x8*)&lsB[cur][ro];
      bf16x8 b1 = *(const bf16x8*)&lsB[cur][8192 + ro];
#pragma unroll
      for (int mf = 0; mf < 4; ++mf) {
        acc[mf][nf] = __builtin_amdgcn_mfma_f32_16x16x32_bf16(a[mf][0], b0, acc[mf][nf], 0, 0, 0);
        acc[mf][nf] = __builtin_amdgcn_mfma_f32_16x16x32_bf16(a[mf][1], b0, acc[mf][nf], 0, 0, 0);
        acc[mf][nf] = __builtin_amdgcn_mfma_f32_16x16x32_bf16(a[mf][0], b1, acc[mf][nf], 0, 0, 0);
      }
    }
    if (more) {
      SPLITB();
      WRITEB(cur ^ 1);
    }
    asm volatile("s_waitcnt vmcnt(0) lgkmcnt(0)" ::: "memory");
    if (t + 2 < nt) LOADB();
    __builtin_amdgcn_sched_barrier(0);
    __builtin_amdgcn_s_barrier();
    __builtin_amdgcn_sched_barrier(0);
    cur ^= 1;
  }

#pragma unroll
  for (int mf = 0; mf < 4; ++mf)
#pragma unroll
    for (int nf = 0; nf < 8; ++nf)
#pragma unroll
      for (int r = 0; r < 4; ++r) {
        int m = m0 + wm * 64 + mf * 16 + c0 * 4 + r;
        int n = n0 + wn * 128 + nf * 16 + l15;
        outp[((size_t)blockIdx.z * Mrows + m) * 8192 + n] = acc[mf][nf][r];
      }
}

// ---- gates: sums nparts z-partials (+ optional zx0/zx1), all-tanh; czero treats
// c-in as 0 (t=0). Writes h split pair + optional conv2-gather split pair.
__global__ void k_gates(const float* __restrict__ zpart, int nparts,
                        const float* __restrict__ zx0, const float* __restrict__ zx1,
                        const float* __restrict__ bias, float* __restrict__ c, int czero,
                        unsigned short* __restrict__ Hh, unsigned short* __restrict__ Hm,
                        unsigned short* __restrict__ ydh, unsigned short* __restrict__ ydm,
                        int s) {
  int i = blockIdx.x * 256 + threadIdx.x;
  int b = i >> 11, u = i & 2047;
  float g4[4];
#pragma unroll
  for (int gi = 0; gi < 4; ++gi) {
    int n = u + gi * 2048;
    float v = bias[n];
    for (int p = 0; p < nparts; ++p) v += zpart[((size_t)p * 256 + b) * 8192 + n];
    if (zx0) v += zx0[(size_t)b * 8192 + n];
    if (zx1) v += zx1[(size_t)b * 8192 + n];
    g4[gi] = tanhf(v);
  }
  float cold = czero ? 0.f : c[i];
  float cn = g4[1] * cold + g4[0] * g4[2];
  c[i] = cn;
  float h = g4[3] * tanhf(cn);
  unsigned short hh, hm;
  split2(h, hh, hm);
  Hh[i] = hh; Hm[i] = hm;
  if (ydh) {
    size_t a = (size_t)(b * 16 + (u >> 9) * 4 + s) * 512 + (u & 511);
    ydh[a] = hh; ydm[a] = hm;
  }
}

// ---- IN+lrelu after conv1 (sums 2 partials [4096][512]), writes steps split pair
__global__ void k_inorm1(const float* __restrict__ part, const float* __restrict__ gamma,
                         const float* __restrict__ beta,
                         unsigned short* __restrict__ Sh, unsigned short* __restrict__ Sm) {
  int d = blockIdx.y * 256 + threadIdx.x;
  int b = blockIdx.x;
  float v[16], s = 0.f, s2 = 0.f;
#pragma unroll
  for (int p = 0; p < 16; ++p) {
    float xv = part[((size_t)(b * 16 + p)) * 512 + d] +
               part[((size_t)(4096 + b * 16 + p)) * 512 + d];
    v[p] = xv; s += xv; s2 += xv * xv;
  }
  float mean = s * (1.f / 16.f);
  float var = s2 * (1.f / 16.f) - mean * mean;
  float sc = gamma[d] * rsqrtf(var + EPSN);
  float bt = beta[d];
#pragma unroll
  for (int p = 0; p < 16; ++p) {
    int hh = p >> 2, w = p & 3;
    float xn = (v[p] - mean) * sc + bt;
    xn = xn >= 0.f ? xn : 0.2f * xn;
    size_t a = (size_t)(w * 256 + b) * 2048 + hh * 512 + d;
    unsigned short th, tm;
    split2(xn, th, tm);
    Sh[a] = th; Sm[a] = tm;
  }
}

// ---- IN+lrelu after conv2 (single partial [4096][1024]), writes final out
__global__ void k_inorm2(const float* __restrict__ part, const float* __restrict__ gamma,
                         const float* __restrict__ beta, float* __restrict__ out) {
  int o = blockIdx.y * 256 + threadIdx.x;
  int b = blockIdx.x;
  float v[16], s = 0.f, s2 = 0.f;
#pragma unroll
  for (int p = 0; p < 16; ++p) {
    float xv = part[((size_t)(b * 16 + p)) * 1024 + o];
    v[p] = xv; s += xv; s2 += xv * xv;
  }
  float mean = s * (1.f / 16.f);
  float var = s2 * (1.f / 16.f) - mean * mean;
  float sc = gamma[o] * rsqrtf(var + EPSN);
  float bt = beta[o];
#pragma unroll
  for (int p = 0; p < 16; ++p) {
    float xn = (v[p] - mean) * sc + bt;
    xn = xn >= 0.f ? xn : 0.2f * xn;
    out[((size_t)(b * 16 + p)) * 1024 + o] = xn;
  }
}

extern "C" void kernel_launch(void* const* d_in, const int* in_sizes, int n_in,
                              void* d_out, int out_size, void* d_ws, size_t ws_size,
                              hipStream_t stream) {
  (void)in_sizes; (void)n_in; (void)out_size;
  const float* x     = (const float*)d_in[0];
  const float* w1    = (const float*)d_in[1];
  const float* g1    = (const float*)d_in[2];
  const float* b1    = (const float*)d_in[3];
  const float* enc_k = (const float*)d_in[4];
  const float* enc_r = (const float*)d_in[5];
  const float* enc_b = (const float*)d_in[6];
  const float* dec_k = (const float*)d_in[7];
  const float* dec_r = (const float*)d_in[8];
  const float* dec_b = (const float*)d_in[9];
  const float* w2    = (const float*)d_in[10];
  const float* g2    = (const float*)d_in[11];
  const float* b2    = (const float*)d_in[12];
  float* out = (float*)d_out;

  if (ws_size < 176160768ULL) return;  // 168 MiB known-good bound

  // Layout — same regions as r13-r20 (ZX = 2 partials [1024][8192] = 64Mi):
  char* base = (char*)d_ws;
  float* zpart = (float*)base;
  float* ZX    = (float*)(base + (64ull << 20));
  char*  xreg  = base + (128ull << 20);
  unsigned short* xh  = (unsigned short*)xreg;               // [4096][1024]
  unsigned short* xm  = (unsigned short*)(xreg + (8ull << 20));
  unsigned short* ydh = (unsigned short*)xreg;               // [4096][512]
  unsigned short* ydm = (unsigned short*)(xreg + (4ull << 20));
  unsigned short* h1s = (unsigned short*)(xreg + (8ull << 20));
  unsigned short* h2s = (unsigned short*)(xreg + (10ull << 20));
  unsigned short* y0s = (unsigned short*)(xreg + (12ull << 20));
  unsigned short* y1s = (unsigned short*)(xreg + (14ull << 20));
  unsigned short* st2 = (unsigned short*)(base + (144ull << 20));
  float* c1 = (float*)(base + (152ull << 20));
  float* c2 = (float*)(base + (154ull << 20));

  const size_t SP = 1024ull * 2048;   // steps split stride
  const size_t HP = 256ull * 2048;    // h split stride
  unsigned short *sth = st2, *stm = st2 + SP;
  unsigned short *h1h = h1s, *h1m = h1s + HP;
  unsigned short *h2h = h2s, *h2m = h2s + HP;
  unsigned short* ys[2] = {y0s, y1s};

  // conv1 via kgm (128^2): split x ([4096][1024] = [m][k]), 2 k-partials
  k_splitx<<<4096, 256, 0, stream>>>(x, xh, xm, 1048576);
  kgm<<<dim3(4, 32, 2), 256, 0, stream>>>(xh, xm, xh, xm, w1, w1,
                                          1024, 512, 4096, 512, zpart);
  k_inorm1<<<dim3(256, 2), 256, 0, stream>>>(zpart, g1, b1, sth, stm);

  // ZX = steps @ enc_k (all 4 timesteps): BN=256 kernel, grid (32,4,2), 2 partials
  kgm2b<<<dim3(32, 4, 2), 512, 0, stream>>>(sth, stm, sth, stm, enc_k, enc_k,
                                            1024, 1024, ZX);

  // encoder t=0: h1=c1=h2=c2=0 -> layer1 GEMM skipped; layer2 K=2048 only
  k_gates<<<2048, 256, 0, stream>>>(nullptr, 0, ZX, ZX + SP * 4, enc_b, c1, 1,
                                    h1h, h1m, nullptr, nullptr, 0);
  kgm2<<<dim3(64, 1, 2), 512, 0, stream>>>(h1h, h1m, h1h, h1m, enc_k, enc_k,
                                           256, 1024, zpart);
  k_gates<<<2048, 256, 0, stream>>>(zpart, 2, nullptr, nullptr, enc_b, c2, 1,
                                    h2h, h2m, nullptr, nullptr, 0);
  // encoder t=1..3
  for (int t = 1; t < 4; ++t) {
    kgm2<<<dim3(64, 1, 4), 512, 0, stream>>>(h1h, h1m, h1h, h1m, enc_r, enc_r,
                                             256, 512, zpart);
    k_gates<<<2048, 256, 0, stream>>>(zpart, 4, ZX + (size_t)t * 256 * 8192,
                                      ZX + SP * 4 + (size_t)t * 256 * 8192, enc_b, c1, 0,
                                      h1h, h1m, nullptr, nullptr, 0);
    kgm2<<<dim3(64, 1, 4), 512, 0, stream>>>(h1h, h1m, h2h, h2m, enc_k, enc_r,
                                             256, 1024, zpart);
    k_gates<<<2048, 256, 0, stream>>>(zpart, 4, nullptr, nullptr, enc_b, c2, 0,
                                      h2h, h2m, nullptr, nullptr, 0);
  }
  // decoder
  for (int s = 0; s < 4; ++s) {
    const unsigned short *xhh, *xmm, *ph, *pm;
    if (s == 0) {
      xhh = sth + 768 * 2048; xmm = stm + 768 * 2048;
      ph = h2h; pm = h2m;
    } else {
      unsigned short* pr = ys[(s - 1) & 1];
      xhh = pr; xmm = pr + HP;
      ph = pr; pm = pr + HP;
    }
    kgm2<<<dim3(64, 1, 4), 512, 0, stream>>>(xhh, xmm, h1h, h1m, dec_k, dec_r,
                                             256, 1024, zpart);
    k_gates<<<2048, 256, 0, stream>>>(zpart, 4, nullptr, nullptr, dec_b, c1, 0,
                                      h1h, h1m, nullptr, nullptr, 0);
    kgm2<<<dim3(64, 1, 4), 512, 0, stream>>>(h1h, h1m, ph, pm, dec_k, dec_r,
                                             256, 1024, zpart);
    unsigned short* cur = ys[s & 1];
    k_gates<<<2048, 256, 0, stream>>>(zpart, 4, nullptr, nullptr, dec_b, c2, 0,
                                      cur, cur + HP, ydh, ydm, s);
  }

  // conv2 via kgm (128^2): gathered y split pair [4096][512] @ w2[512][1024], 1 partial
  kgm<<<dim3(8, 32, 1), 256, 0, stream>>>(ydh, ydm, ydh, ydm, w2, w2,
                                          512, 1024, 4096, 512, zpart);
  k_inorm2<<<dim3(256, 4), 256, 0, stream>>>(zpart, g2, b2, out);
}

// Round 24
// 1128.347 us; speedup vs baseline: 1.4692x; 1.0104x over previous
//
#include <hip/hip_runtime.h>

#define EPSN 1e-6f

typedef __attribute__((ext_vector_type(4))) float f32x4;
typedef __attribute__((ext_vector_type(8))) __bf16 bf16x8;
typedef __attribute__((ext_vector_type(8))) unsigned short us8;
typedef __attribute__((ext_vector_type(4))) unsigned short us4;
typedef __attribute__((ext_vector_type(4))) float f4v;

__device__ __forceinline__ void async16(const void* g, void* l) {
  __builtin_amdgcn_global_load_lds(
      (const __attribute__((address_space(1))) unsigned int*)g,
      (__attribute__((address_space(3))) unsigned int*)l, 16, 0, 0);
}

// 2-level bf16 split: v ~= h + m with residual <= 2^-18 rel
__device__ __forceinline__ void split2(float v, unsigned short& h, unsigned short& m) {
  __bf16 a = (__bf16)v;  float fa = (float)a;
  __bf16 b = (__bf16)(v - fa);
  h = __builtin_bit_cast(unsigned short, a);
  m = __builtin_bit_cast(unsigned short, b);
}

// ---- x -> split pair (elementwise)
__global__ void k_splitx(const float* __restrict__ in, unsigned short* __restrict__ oh,
                         unsigned short* __restrict__ om, int n4) {
  int i = blockIdx.x * 256 + threadIdx.x;
  if (i < n4) {
    f4v v = ((const f4v*)in)[i];
    us4 h, m;
#pragma unroll
    for (int j = 0; j < 4; ++j) { unsigned short a, b; split2(v[j], a, b); h[j] = a; m[j] = b; }
    ((us4*)oh)[i] = h;
    ((us4*)om)[i] = m;
  }
}

// ==== kgm: 128^2-tile 3-term split GEMM (hh+hm+mh) — convs only (r18-proven) ====
__global__ __launch_bounds__(256, 2) void kgm(
    const unsigned short* __restrict__ Ah0, const unsigned short* __restrict__ Am0,
    const unsigned short* __restrict__ Ah1, const unsigned short* __restrict__ Am1,
    const float* __restrict__ B0, const float* __restrict__ B1,
    int lda, int N, int Mrows, int kchunk, float* __restrict__ outp) {
  __shared__ unsigned short lsA[2][2 * 128 * 32];
  __shared__ unsigned short lsB[2 * 4 * 128 * 8];
  const int tid = threadIdx.x, lane = tid & 63, wid = tid >> 6;
  const int n0 = blockIdx.x * 128, m0 = blockIdx.y * 128;
  const int kbase = blockIdx.z * kchunk;

  const unsigned short *Ah, *Am; const float* B; int koff;
  if (kbase < 2048) { Ah = Ah0; Am = Am0; B = B0; koff = kbase; }
  else              { Ah = Ah1; Am = Am1; B = B1; koff = kbase - 2048; }
  const int nt = kchunk >> 5;

  const unsigned short* asrc[4];
  int adst[4];
#pragma unroll
  for (int j = 0; j < 4; ++j) {
    int idx = j * 256 + tid;
    int s = idx >> 9, rem = idx & 511, row = rem >> 2, slot = idx & 3;
    const unsigned short* base = (s == 0) ? Ah : Am;
    asrc[j] = base + (size_t)(m0 + row) * lda + koff + ((slot ^ ((row >> 1) & 3)) << 3);
    adst[j] = (j * 256 + (tid & ~63)) * 16;
  }
  auto STAGEA = [&](int buf) {
#pragma unroll
    for (int j = 0; j < 4; ++j) {
      async16(asrc[j], (char*)&lsA[buf][0] + adst[j]);
      asrc[j] += 32;
    }
  };

  const int kq = tid >> 6, nn = tid & 63;
  const float* bptr = B + (size_t)(koff + kq * 8) * N + n0 + nn;
  const int bo0 = kq * 1024 + nn * 8;
  const int bo1 = kq * 1024 + (nn + 64) * 8;
  float bwa[8], bwb[8];
  us8 bs[4];
  auto LOADB = [&]() {
#pragma unroll
    for (int r = 0; r < 8; ++r) {
      bwa[r] = bptr[(size_t)r * N];
      bwb[r] = bptr[(size_t)r * N + 64];
    }
    bptr += (size_t)32 * N;
  };
  auto SPLITB = [&]() {
#pragma unroll
    for (int r = 0; r < 8; ++r) {
      unsigned short h, m;
      split2(bwa[r], h, m);
      bs[0][r] = h; bs[1][r] = m;
      split2(bwb[r], h, m);
      bs[2][r] = h; bs[3][r] = m;
    }
  };
  auto WRITEB = [&]() {
    *(us8*)&lsB[bo0] = bs[0];
    *(us8*)&lsB[4096 + bo0] = bs[1];
    *(us8*)&lsB[bo1] = bs[2];
    *(us8*)&lsB[4096 + bo1] = bs[3];
  };

  const int c0 = lane >> 4, l15 = lane & 15;
  const int wm = wid >> 1, wn = wid & 1;
  f32x4 acc[4][4];
#pragma unroll
  for (int i = 0; i < 4; ++i)
#pragma unroll
    for (int j = 0; j < 4; ++j) acc[i][j] = (f32x4){0, 0, 0, 0};

  STAGEA(0);
  LOADB();
  SPLITB();
  int abuf = 0;
  for (int t = 0; t < nt; ++t) {
    __syncthreads();
    WRITEB();
    __syncthreads();
    bool more = (t + 1 < nt);
    if (more) {
      STAGEA(abuf ^ 1);
      LOADB();
    }
    bf16x8 a[4][2];
#pragma unroll
    for (int mf = 0; mf < 4; ++mf) {
      int m = wm * 64 + mf * 16 + l15;
      int ro = m * 32 + ((c0 ^ ((m >> 1) & 3)) << 3);
      a[mf][0] = *(const bf16x8*)&lsA[abuf][ro];
      a[mf][1] = *(const bf16x8*)&lsA[abuf][4096 + ro];
    }
#pragma unroll
    for (int nf = 0; nf < 4; ++nf) {
      int ro = c0 * 1024 + (wn * 64 + nf * 16 + l15) * 8;
      bf16x8 b0 = *(const bf16x8*)&lsB[ro];
      bf16x8 b1 = *(const bf16x8*)&lsB[4096 + ro];
#pragma unroll
      for (int mf = 0; mf < 4; ++mf) {
        acc[mf][nf] = __builtin_amdgcn_mfma_f32_16x16x32_bf16(a[mf][0], b0, acc[mf][nf], 0, 0, 0);
        acc[mf][nf] = __builtin_amdgcn_mfma_f32_16x16x32_bf16(a[mf][1], b0, acc[mf][nf], 0, 0, 0);
        acc[mf][nf] = __builtin_amdgcn_mfma_f32_16x16x32_bf16(a[mf][0], b1, acc[mf][nf], 0, 0, 0);
      }
    }
    if (more) SPLITB();
    abuf ^= 1;
  }

#pragma unroll
  for (int mf = 0; mf < 4; ++mf)
#pragma unroll
    for (int nf = 0; nf < 4; ++nf)
#pragma unroll
      for (int r = 0; r < 4; ++r) {
        int m = m0 + wm * 64 + mf * 16 + c0 * 4 + r;
        int n = n0 + wn * 64 + nf * 16 + l15;
        outp[((size_t)blockIdx.z * Mrows + m) * N + n] = acc[mf][nf][r];
      }
}

// ==== kgm2: 256m x 128n tile — all cell GEMMs (r23 schedule: single barrier,
// cross-barrier B prefetch, A gload_lds dbuf). kbase<2048 -> A0/B0 else A1/B1.
__global__ __launch_bounds__(512, 1) void kgm2(
    const unsigned short* __restrict__ Ah0, const unsigned short* __restrict__ Am0,
    const unsigned short* __restrict__ Ah1, const unsigned short* __restrict__ Am1,
    const float* __restrict__ B0, const float* __restrict__ B1,
    int Mrows, int kchunk, float* __restrict__ outp) {
  __shared__ unsigned short lsA[2][2 * 256 * 32];
  __shared__ unsigned short lsB[2][2 * 4 * 128 * 8];
  const int tid = threadIdx.x, lane = tid & 63, wid = tid >> 6;
  const int n0 = blockIdx.x * 128, m0 = blockIdx.y * 256;
  const int kbase = blockIdx.z * kchunk;

  const unsigned short *Ah, *Am; const float* B; int koff;
  if (kbase < 2048) { Ah = Ah0; Am = Am0; B = B0; koff = kbase; }
  else              { Ah = Ah1; Am = Am1; B = B1; koff = kbase - 2048; }
  const int nt = kchunk >> 5;

  const unsigned short* asrc[4];
  int adst[4];
#pragma unroll
  for (int j = 0; j < 4; ++j) {
    int idx = j * 512 + tid;
    int s = idx >> 10, rem = idx & 1023, row = rem >> 2, slot = idx & 3;
    const unsigned short* base = (s == 0) ? Ah : Am;
    asrc[j] = base + (size_t)(m0 + row) * 2048 + koff + ((slot ^ ((row >> 1) & 3)) << 3);
    adst[j] = (j * 512 + (tid & ~63)) * 16;
  }
  auto STAGEA = [&](int buf) {
#pragma unroll
    for (int j = 0; j < 4; ++j) {
      async16(asrc[j], (char*)&lsA[buf][0] + adst[j]);
      asrc[j] += 32;
    }
  };

  const int kq = tid >> 7, nn = tid & 127;
  const float* bptr = B + (size_t)(koff + kq * 8) * 8192 + n0 + nn;
  const int bo = kq * 1024 + nn * 8;
  float bw[8];
  us8 bsh, bsm;
  auto LOADB = [&]() {
#pragma unroll
    for (int r = 0; r < 8; ++r) bw[r] = bptr[(size_t)r * 8192];
    bptr += (size_t)32 * 8192;
  };
  auto SPLITB = [&]() {
#pragma unroll
    for (int r = 0; r < 8; ++r) {
      unsigned short h, m;
      split2(bw[r], h, m);
      bsh[r] = h; bsm[r] = m;
    }
  };
  auto WRITEB = [&](int buf) {
    *(us8*)&lsB[buf][bo] = bsh;
    *(us8*)&lsB[buf][4096 + bo] = bsm;
  };

  const int c0 = lane >> 4, l15 = lane & 15;
  const int wm = wid >> 1, wn = wid & 1;
  f32x4 acc[4][4];
#pragma unroll
  for (int i = 0; i < 4; ++i)
#pragma unroll
    for (int j = 0; j < 4; ++j) acc[i][j] = (f32x4){0, 0, 0, 0};

  // prologue: B(0)->lsB[0], A(0) DMA; B(1) issued after drain (in flight over barrier)
  LOADB();
  STAGEA(0);
  SPLITB();
  WRITEB(0);
  asm volatile("s_waitcnt vmcnt(0) lgkmcnt(0)" ::: "memory");
  LOADB();  // B(1)
  __builtin_amdgcn_sched_barrier(0);
  __builtin_amdgcn_s_barrier();
  __builtin_amdgcn_sched_barrier(0);

  int cur = 0;
  for (int t = 0; t < nt; ++t) {
    bool more = (t + 1 < nt);
    if (more) STAGEA(cur ^ 1);  // A(t+1) DMA; drained at this iter's vmcnt(0)
    bf16x8 a[4][2];
#pragma unroll
    for (int mf = 0; mf < 4; ++mf) {
      int m = wm * 64 + mf * 16 + l15;
      int ro = m * 32 + ((c0 ^ ((m >> 1) & 3)) << 3);
      a[mf][0] = *(const bf16x8*)&lsA[cur][ro];
      a[mf][1] = *(const bf16x8*)&lsA[cur][8192 + ro];
    }
#pragma unroll
    for (int nf = 0; nf < 4; ++nf) {
      int ro = c0 * 1024 + (wn * 64 + nf * 16 + l15) * 8;
      bf16x8 b0 = *(const bf16x8*)&lsB[cur][ro];
      bf16x8 b1 = *(const bf16x8*)&lsB[cur][4096 + ro];
#pragma unroll
      for (int mf = 0; mf < 4; ++mf) {
        acc[mf][nf] = __builtin_amdgcn_mfma_f32_16x16x32_bf16(a[mf][0], b0, acc[mf][nf], 0, 0, 0);
        acc[mf][nf] = __builtin_amdgcn_mfma_f32_16x16x32_bf16(a[mf][1], b0, acc[mf][nf], 0, 0, 0);
        acc[mf][nf] = __builtin_amdgcn_mfma_f32_16x16x32_bf16(a[mf][0], b1, acc[mf][nf], 0, 0, 0);
      }
    }
    if (more) {
      SPLITB();          // bw = B(t+1), loaded last iter: cover = barrier + compute
      WRITEB(cur ^ 1);
    }
    asm volatile("s_waitcnt vmcnt(0) lgkmcnt(0)" ::: "memory");  // drain A DMA + ds_writes
    if (t + 2 < nt) LOADB();  // B(t+2): issued post-drain, rides across the barrier
    __builtin_amdgcn_sched_barrier(0);
    __builtin_amdgcn_s_barrier();
    __builtin_amdgcn_sched_barrier(0);
    cur ^= 1;
  }

  // C/D: col = lane&15, row = (lane>>4)*4 + r  [m89-verified]
#pragma unroll
  for (int mf = 0; mf < 4; ++mf)
#pragma unroll
    for (int nf = 0; nf < 4; ++nf)
#pragma unroll
      for (int r = 0; r < 4; ++r) {
        int m = m0 + wm * 64 + mf * 16 + c0 * 4 + r;
        int n = n0 + wn * 64 + nf * 16 + l15;
        outp[((size_t)blockIdx.z * Mrows + m) * 8192 + n] = acc[mf][nf][r];
      }
}

// ---- gates: sums nparts z-partials, all-tanh; czero treats c-in as 0.
// Writes h split pair + optional conv2-gather split pair.
__global__ void k_gates(const float* __restrict__ zpart, int nparts,
                        const float* __restrict__ bias, float* __restrict__ c, int czero,
                        unsigned short* __restrict__ Hh, unsigned short* __restrict__ Hm,
                        unsigned short* __restrict__ ydh, unsigned short* __restrict__ ydm,
                        int s) {
  int i = blockIdx.x * 256 + threadIdx.x;
  int b = i >> 11, u = i & 2047;
  float g4[4];
#pragma unroll
  for (int gi = 0; gi < 4; ++gi) {
    int n = u + gi * 2048;
    float v = bias[n];
    for (int p = 0; p < nparts; ++p) v += zpart[((size_t)p * 256 + b) * 8192 + n];
    g4[gi] = tanhf(v);
  }
  float cold = czero ? 0.f : c[i];
  float cn = g4[1] * cold + g4[0] * g4[2];
  c[i] = cn;
  float h = g4[3] * tanhf(cn);
  unsigned short hh, hm;
  split2(h, hh, hm);
  Hh[i] = hh; Hm[i] = hm;
  if (ydh) {
    size_t a = (size_t)(b * 16 + (u >> 9) * 4 + s) * 512 + (u & 511);
    ydh[a] = hh; ydm[a] = hm;
  }
}

// ---- IN+lrelu after conv1 (sums 2 partials [4096][512]), writes steps split pair
__global__ void k_inorm1(const float* __restrict__ part, const float* __restrict__ gamma,
                         const float* __restrict__ beta,
                         unsigned short* __restrict__ Sh, unsigned short* __restrict__ Sm) {
  int d = blockIdx.y * 256 + threadIdx.x;
  int b = blockIdx.x;
  float v[16], s = 0.f, s2 = 0.f;
#pragma unroll
  for (int p = 0; p < 16; ++p) {
    float xv = part[((size_t)(b * 16 + p)) * 512 + d] +
               part[((size_t)(4096 + b * 16 + p)) * 512 + d];
    v[p] = xv; s += xv; s2 += xv * xv;
  }
  float mean = s * (1.f / 16.f);
  float var = s2 * (1.f / 16.f) - mean * mean;
  float sc = gamma[d] * rsqrtf(var + EPSN);
  float bt = beta[d];
#pragma unroll
  for (int p = 0; p < 16; ++p) {
    int hh = p >> 2, w = p & 3;
    float xn = (v[p] - mean) * sc + bt;
    xn = xn >= 0.f ? xn : 0.2f * xn;
    size_t a = (size_t)(w * 256 + b) * 2048 + hh * 512 + d;
    unsigned short th, tm;
    split2(xn, th, tm);
    Sh[a] = th; Sm[a] = tm;
  }
}

// ---- IN+lrelu after conv2 (single partial [4096][1024]), writes final out
__global__ void k_inorm2(const float* __restrict__ part, const float* __restrict__ gamma,
                         const float* __restrict__ beta, float* __restrict__ out) {
  int o = blockIdx.y * 256 + threadIdx.x;
  int b = blockIdx.x;
  float v[16], s = 0.f, s2 = 0.f;
#pragma unroll
  for (int p = 0; p < 16; ++p) {
    float xv = part[((size_t)(b * 16 + p)) * 1024 + o];
    v[p] = xv; s += xv; s2 += xv * xv;
  }
  float mean = s * (1.f / 16.f);
  float var = s2 * (1.f / 16.f) - mean * mean;
  float sc = gamma[o] * rsqrtf(var + EPSN);
  float bt = beta[o];
#pragma unroll
  for (int p = 0; p < 16; ++p) {
    float xn = (v[p] - mean) * sc + bt;
    xn = xn >= 0.f ? xn : 0.2f * xn;
    out[((size_t)(b * 16 + p)) * 1024 + o] = xn;
  }
}

extern "C" void kernel_launch(void* const* d_in, const int* in_sizes, int n_in,
                              void* d_out, int out_size, void* d_ws, size_t ws_size,
                              hipStream_t stream) {
  (void)in_sizes; (void)n_in; (void)out_size;
  const float* x     = (const float*)d_in[0];
  const float* w1    = (const float*)d_in[1];
  const float* g1    = (const float*)d_in[2];
  const float* b1    = (const float*)d_in[3];
  const float* enc_k = (const float*)d_in[4];
  const float* enc_r = (const float*)d_in[5];
  const float* enc_b = (const float*)d_in[6];
  const float* dec_k = (const float*)d_in[7];
  const float* dec_r = (const float*)d_in[8];
  const float* dec_b = (const float*)d_in[9];
  const float* w2    = (const float*)d_in[10];
  const float* g2    = (const float*)d_in[11];
  const float* b2    = (const float*)d_in[12];
  float* out = (float*)d_out;

  if (ws_size < 176160768ULL) return;  // 168 MiB known-good bound

  // Layout — r23 regions minus ZX (now unused):
  char* base = (char*)d_ws;
  float* zpart = (float*)base;                        // [0,64Mi) cell/conv partials
  char*  xreg  = base + (128ull << 20);
  unsigned short* xh  = (unsigned short*)xreg;               // [4096][1024]
  unsigned short* xm  = (unsigned short*)(xreg + (8ull << 20));
  unsigned short* ydh = (unsigned short*)xreg;               // [4096][512]
  unsigned short* ydm = (unsigned short*)(xreg + (4ull << 20));
  unsigned short* h1s = (unsigned short*)(xreg + (8ull << 20));
  unsigned short* h2s = (unsigned short*)(xreg + (10ull << 20));
  unsigned short* y0s = (unsigned short*)(xreg + (12ull << 20));
  unsigned short* y1s = (unsigned short*)(xreg + (14ull << 20));
  unsigned short* st2 = (unsigned short*)(base + (144ull << 20));
  float* c1 = (float*)(base + (152ull << 20));
  float* c2 = (float*)(base + (154ull << 20));

  const size_t SP = 1024ull * 2048;   // steps split stride
  const size_t HP = 256ull * 2048;    // h split stride
  unsigned short *sth = st2, *stm = st2 + SP;
  unsigned short *h1h = h1s, *h1m = h1s + HP;
  unsigned short *h2h = h2s, *h2m = h2s + HP;
  unsigned short* ys[2] = {y0s, y1s};

  // conv1 via kgm (128^2): split x ([4096][1024] = [m][k]), 2 k-partials
  k_splitx<<<4096, 256, 0, stream>>>(x, xh, xm, 1048576);
  kgm<<<dim3(4, 32, 2), 256, 0, stream>>>(xh, xm, xh, xm, w1, w1,
                                          1024, 512, 4096, 512, zpart);
  k_inorm1<<<dim3(256, 2), 256, 0, stream>>>(zpart, g1, b1, sth, stm);

  // encoder t=0 (states zero): layer1 = steps0@enc_k (K=2048, z=4)
  kgm2<<<dim3(64, 1, 4), 512, 0, stream>>>(sth, stm, sth, stm, enc_k, enc_k,
                                           256, 512, zpart);
  k_gates<<<2048, 256, 0, stream>>>(zpart, 4, enc_b, c1, 1,
                                    h1h, h1m, nullptr, nullptr, 0);
  // layer2 = h1@enc_k (K=2048, z=4)
  kgm2<<<dim3(64, 1, 4), 512, 0, stream>>>(h1h, h1m, h1h, h1m, enc_k, enc_k,
                                           256, 512, zpart);
  k_gates<<<2048, 256, 0, stream>>>(zpart, 4, enc_b, c2, 1,
                                    h2h, h2m, nullptr, nullptr, 0);
  // encoder t=1..3: layer1 = steps[t]@enc_k + h1@enc_r (K=4096 fused)
  for (int t = 1; t < 4; ++t) {
    const unsigned short* sh = sth + (size_t)t * 256 * 2048;
    const unsigned short* sm = stm + (size_t)t * 256 * 2048;
    kgm2<<<dim3(64, 1, 4), 512, 0, stream>>>(sh, sm, h1h, h1m, enc_k, enc_r,
                                             256, 1024, zpart);
    k_gates<<<2048, 256, 0, stream>>>(zpart, 4, enc_b, c1, 0,
                                      h1h, h1m, nullptr, nullptr, 0);
    kgm2<<<dim3(64, 1, 4), 512, 0, stream>>>(h1h, h1m, h2h, h2m, enc_k, enc_r,
                                             256, 1024, zpart);
    k_gates<<<2048, 256, 0, stream>>>(zpart, 4, enc_b, c2, 0,
                                      h2h, h2m, nullptr, nullptr, 0);
  }
  // decoder
  for (int s = 0; s < 4; ++s) {
    const unsigned short *xhh, *xmm, *ph, *pm;
    if (s == 0) {
      xhh = sth + 768 * 2048; xmm = stm + 768 * 2048;
      ph = h2h; pm = h2m;
    } else {
      unsigned short* pr = ys[(s - 1) & 1];
      xhh = pr; xmm = pr + HP;
      ph = pr; pm = pr + HP;
    }
    kgm2<<<dim3(64, 1, 4), 512, 0, stream>>>(xhh, xmm, h1h, h1m, dec_k, dec_r,
                                             256, 1024, zpart);
    k_gates<<<2048, 256, 0, stream>>>(zpart, 4, dec_b, c1, 0,
                                      h1h, h1m, nullptr, nullptr, 0);
    kgm2<<<dim3(64, 1, 4), 512, 0, stream>>>(h1h, h1m, ph, pm, dec_k, dec_r,
                                             256, 1024, zpart);
    unsigned short* cur = ys[s & 1];
    k_gates<<<2048, 256, 0, stream>>>(zpart, 4, dec_b, c2, 0,
                                      cur, cur + HP, ydh, ydm, s);
  }

  // conv2 via kgm (128^2): gathered y split pair [4096][512] @ w2[512][1024], 1 partial
  kgm<<<dim3(8, 32, 1), 256, 0, stream>>>(ydh, ydm, ydh, ydm, w2, w2,
                                          512, 1024, 4096, 512, zpart);
  k_inorm2<<<dim3(256, 4), 256, 0, stream>>>(zpart, g2, b2, out);
}